// Round 13
// baseline (219.382 us; speedup 1.0000x reference)
//
#include <hip/hip_runtime.h>

// ---------- types ----------
typedef __bf16 bf16x8 __attribute__((ext_vector_type(8)));
typedef float  f32x4  __attribute__((ext_vector_type(4)));
typedef unsigned short u16x8 __attribute__((ext_vector_type(8)));

#define IN_CH  256
#define OUT_CH 256
#define HIDDEN 2048
#define NB     8
#define NT     4000
#define NROW   32000   // NB*NT
#define F1LD   34      // f1t leading dim (odd word stride 17 -> spread banks)

__device__ __forceinline__ unsigned short bfbits(float f) {
    __bf16 h = (__bf16)f;                       // native cvt (RTNE)
    return *reinterpret_cast<unsigned short*>(&h);
}
__device__ __forceinline__ float bf2f(unsigned short h) {
    return __uint_as_float(((unsigned)h) << 16);
}

#define GLOAD_LDS16(g, l) \
    __builtin_amdgcn_global_load_lds((const __attribute__((address_space(1))) void*)(g), \
                                     (__attribute__((address_space(3))) void*)(l), 16, 0, 0)

// ---------- 1. fp32 -> bf16 convert (both weight tensors, one launch) ----------
__global__ void cvt_kernel(const float* __restrict__ w1,
                           unsigned short* __restrict__ w1o,
                           const float* __restrict__ w2,
                           unsigned short* __restrict__ w2o) {
    int i = blockIdx.x * blockDim.x + threadIdx.x;   // 0..262143
    const float* in;
    unsigned short* outp;
    int j;
    if (i < 131072) { in = w1; outp = w1o; j = i; }
    else            { in = w2; outp = w2o; j = i - 131072; }
    float4 v = reinterpret_cast<const float4*>(in)[j];
    ushort4 o;
    o.x = bfbits(v.x); o.y = bfbits(v.y); o.z = bfbits(v.z); o.w = bfbits(v.w);
    reinterpret_cast<ushort4*>(outp)[j] = o;
}

// ---------- 2. partial mean/var reduction over T ----------
__global__ void reduce_kernel(const float* __restrict__ x,
                              float* __restrict__ psum, float* __restrict__ psq) {
    int c = threadIdx.x;
    int blk = blockIdx.x;
    int b = blk >> 5, tc = blk & 31;
    const float* base = x + ((size_t)b * NT + tc * 125) * IN_CH + c;
    float s = 0.f, q = 0.f;
    for (int t = 0; t < 125; ++t) {
        float v = base[(size_t)t * IN_CH];
        s += v; q += v * v;
    }
    psum[blk * IN_CH + c] = s;
    psq [blk * IN_CH + c] = q;
}

// ---------- 3. gate: mean/std -> logits -> probs -> losses ----------
__global__ __launch_bounds__(256) void gate_kernel(
    const float* __restrict__ psum, const float* __restrict__ psq,
    const float* __restrict__ gate_w, const float* __restrict__ gate_b,
    const float* __restrict__ tau, float* __restrict__ probs,
    float* __restrict__ losses) {
    __shared__ float gi[NB][2 * IN_CH];
    __shared__ float lgt[16];
    int tid = threadIdx.x;
    for (int b = 0; b < NB; ++b) {
        float s = 0.f, q = 0.f;
        for (int p = 0; p < 32; ++p) {
            s += psum[(b * 32 + p) * IN_CH + tid];
            q += psq [(b * 32 + p) * IN_CH + tid];
        }
        float mean = s * (1.f / 4000.f);
        float var  = (q - s * s * (1.f / 4000.f)) * (1.f / 3999.f);  // ddof=1
        gi[b][tid]          = mean;
        gi[b][IN_CH + tid]  = sqrtf(fmaxf(var, 0.f));
    }
    __syncthreads();
    if (tid < 16) {
        int b = tid >> 1, k = tid & 1;
        float d = 0.f;
        for (int i = 0; i < 2 * IN_CH; ++i) d += gi[b][i] * gate_w[k * 2 * IN_CH + i];
        lgt[tid] = tau[0] * (d + gate_b[k]);
    }
    __syncthreads();
    if (tid == 0) {
        float pr[16];
        float i0 = 0.f, i1 = 0.f, sp = 0.f;
        for (int b = 0; b < NB; ++b) {
            float a = lgt[b * 2], c2 = lgt[b * 2 + 1];
            float mx = fmaxf(a, c2);
            float e0 = expf(a - mx), e1 = expf(c2 - mx);
            float inv = 1.f / (e0 + e1);
            float q0 = e0 * inv, q1 = e1 * inv;
            pr[b * 2] = q0; pr[b * 2 + 1] = q1;
            i0 += q0; i1 += q1;
            float nrm = sqrtf(q0 * q0 + q1 * q1) + 1e-8f;
            sp += (q0 + q1) / nrm;
        }
        losses[0] = 0.1f * sp * (1.f / 8.f);
        i0 *= (1.f / 8.f); i1 *= (1.f / 8.f);
        float meanI = 0.5f * (i0 + i1);
        float stdI  = fabsf(i0 - i1) * 0.7071067811865476f;
        float cv = stdI / (meanI + 1e-8f);
        losses[1] = 0.01f * cv * cv;
        for (int t = 0; t < 16; ++t) probs[t] = pr[t];
    }
}

// ---------- 4. fused GEMM1(relu)+GEMM2 -> mixed output; BK=32, 1 barrier ----
// 500 blocks x 256 threads (4 waves = 2 rb x 2 ch). Wave: 32 rows x 128 oc.
// R12 wall was LDS-port-bound (~75%): 288 b128 LDS reads + 128KB staging
// writes per CU-chunk-pair. This version removes w2 from LDS entirely
// (GEMM2 B-frags read global->reg; w2b is 1MB = L2-resident, loads issued
// before GEMM1 and consumed after -> latency hidden), double-buffers w1
// halves + f1t -> ONE barrier per chunk (vmcnt drain at that barrier also
// completes the next chunk's w1 gload_lds). LDS 74 -> 41.5 KB.
// Regs: xr 128 + b2r 32 + temps ~= 175 arch + 72 acc -> 2 waves/SIMD.
__global__ __launch_bounds__(256, 2) void gemm_kernel(
    const float* __restrict__ x,
    const unsigned short* __restrict__ w1b,   // [2048][256] bf16
    const unsigned short* __restrict__ w2b,   // [256][2048] bf16
    const float* __restrict__ b1,
    const float* __restrict__ probs,          // [8][2]
    unsigned short* __restrict__ mix) {       // [32000][256] bf16 (pre-mixed)
    __shared__ __align__(16) unsigned short w1c[2][32 * 256];   // 32 KB (dbuf)
    __shared__ __align__(16) unsigned short f1t[2][64 * F1LD];  // 8.7 KB (dbuf)

    const int tid   = threadIdx.x;
    const int lane  = tid & 63;
    const int wv    = tid >> 6;       // 0..3
    const int rb    = wv & 1;         // 32-row band
    const int ch    = wv >> 1;        // 0..1 oc half (128 each)
    const int m0    = blockIdx.x * 64;
    const int l15   = lane & 15;
    const int lg    = lane >> 4;      // 0..3
    const int hl    = ch * 16 + l15;  // GEMM1 h-within-chunk (0..31)
    const int hswz  = (hl & 7) << 3;

    // ---- x fragments to registers: xr[rt][kk], rows m0 + rb*32 + rt*16 + l15 ----
    bf16x8 xr[2][8];
#pragma unroll
    for (int rt = 0; rt < 2; ++rt) {
        const float* xrow = x + (size_t)(m0 + rb * 32 + rt * 16 + l15) * IN_CH;
#pragma unroll
        for (int kk = 0; kk < 8; ++kk) {
            float4 v0 = *reinterpret_cast<const float4*>(xrow + kk * 32 + lg * 8);
            float4 v1 = *reinterpret_cast<const float4*>(xrow + kk * 32 + lg * 8 + 4);
            bf16x8 h;
            h[0] = (__bf16)v0.x; h[1] = (__bf16)v0.y; h[2] = (__bf16)v0.z; h[3] = (__bf16)v0.w;
            h[4] = (__bf16)v1.x; h[5] = (__bf16)v1.y; h[6] = (__bf16)v1.z; h[7] = (__bf16)v1.w;
            xr[rt][kk] = h;
        }
    }

    f32x4 acc2[2][8];
#pragma unroll
    for (int rt = 0; rt < 2; ++rt)
#pragma unroll
        for (int t = 0; t < 8; ++t) { acc2[rt][t][0]=0.f; acc2[rt][t][1]=0.f; acc2[rt][t][2]=0.f; acc2[rt][t][3]=0.f; }

    // ---- prologue: stage w1 chunk 0 into half 0 (16 segs of 1 KB, 4/wave) ----
#pragma unroll
    for (int i = 0; i < 4; ++i) {
        int seg = i * 4 + wv;                        // 0..15
        int r1 = seg * 2 + (lane >> 5);              // row within chunk 0..31
        int c1 = ((lane & 31) * 8) ^ ((r1 & 7) << 3);
        GLOAD_LDS16(w1b + r1 * 256 + c1, &w1c[0][seg * 512]);
    }
    __syncthreads();   // chunk-0 w1 staged

#pragma unroll 1
    for (int chunk = 0; chunk < 64; ++chunk) {
        const int cur = chunk & 1;
        const int h0  = chunk * 32;

        // ---- stage next chunk's w1 into the other half ----
        if (chunk < 63) {
            const unsigned short* w1s = w1b + (size_t)(h0 + 32) * IN_CH;
#pragma unroll
            for (int i = 0; i < 4; ++i) {
                int seg = i * 4 + wv;
                int r1 = seg * 2 + (lane >> 5);
                int c1 = ((lane & 31) * 8) ^ ((r1 & 7) << 3);
                GLOAD_LDS16(w1s + r1 * 256 + c1, &w1c[cur ^ 1][seg * 512]);
            }
        }

        // ---- issue w2 B-fragments for THIS chunk (global -> reg, L2-hit) ----
        bf16x8 b2r[8];
#pragma unroll
        for (int t = 0; t < 8; ++t) {
            int oc = ch * 128 + t * 16 + l15;
            b2r[t] = *reinterpret_cast<const bf16x8*>(
                w2b + (size_t)oc * HIDDEN + h0 + lg * 8);
        }

        // ---- GEMM1: f1[64][32] = relu(x @ w1_chunk^T + b1); wave: 32r x 16h ----
        f32x4 acc1[2];
#pragma unroll
        for (int rt = 0; rt < 2; ++rt) { acc1[rt][0]=0.f; acc1[rt][1]=0.f; acc1[rt][2]=0.f; acc1[rt][3]=0.f; }
#pragma unroll
        for (int kk = 0; kk < 8; ++kk) {
            const int kE = kk * 32 + lg * 8;
            bf16x8 bb = *reinterpret_cast<const bf16x8*>(
                &w1c[cur][hl * 256 + (kE ^ hswz)]);
#pragma unroll
            for (int rt = 0; rt < 2; ++rt)
                acc1[rt] = __builtin_amdgcn_mfma_f32_16x16x32_bf16(
                    xr[rt][kk], bb, acc1[rt], 0, 0, 0);
        }
        // bias + relu -> f1t[cur] (col = hl fixed per lane)
        const float bias = b1[h0 + hl];   // L2-hit scalar
#pragma unroll
        for (int rt = 0; rt < 2; ++rt)
#pragma unroll
            for (int r = 0; r < 4; ++r) {
                float v = fmaxf(acc1[rt][r] + bias, 0.f);
                int rr = rb * 32 + rt * 16 + lg * 4 + r;
                f1t[cur][rr * F1LD + hl] = bfbits(v);
            }

        __syncthreads();   // [B] f1t[cur] ready; next w1 half + b2r drained

        // ---- GEMM2: acc2 += f1 @ w2_chunk^T; K=32 -> single k-step ----
        {
            const int kE = lg * 8;
            bf16x8 a2[2];
#pragma unroll
            for (int rt = 0; rt < 2; ++rt)
                a2[rt] = *reinterpret_cast<const bf16x8*>(
                    &f1t[cur][(rb * 32 + rt * 16 + l15) * F1LD + kE]);
#pragma unroll
            for (int t = 0; t < 8; ++t)
#pragma unroll
                for (int rt = 0; rt < 2; ++rt)
                    acc2[rt][t] = __builtin_amdgcn_mfma_f32_16x16x32_bf16(
                        a2[rt], b2r[t], acc2[rt][t], 0, 0, 0);
        }

        if (chunk == 7) {   // hidden 0..255 done: rescale so p0*acc2 = p0*full+p1*small
#pragma unroll
            for (int rt = 0; rt < 2; ++rt)
#pragma unroll
                for (int r = 0; r < 4; ++r) {
                    int rr = m0 + rb * 32 + rt * 16 + lg * 4 + r;
                    int bb = rr / 4000;
                    float p0 = probs[bb * 2], p1 = probs[bb * 2 + 1];
                    float ratio = (p0 + p1) / fmaxf(p0, 1e-30f);
#pragma unroll
                    for (int t = 0; t < 8; ++t)
                        acc2[rt][t][r] *= ratio;
                }
        }
        // no second barrier: next chunk writes f1t[cur^1] and stages w1c[cur]
        // (whose reads completed before [B] this iteration)
    }
    // final: mix = p0 * acc2 (= p0*full + p1*small)
#pragma unroll
    for (int rt = 0; rt < 2; ++rt)
#pragma unroll
        for (int r = 0; r < 4; ++r) {
            int rr = m0 + rb * 32 + rt * 16 + lg * 4 + r;
            int bb = rr / 4000;
            float p0 = probs[bb * 2];
#pragma unroll
            for (int t = 0; t < 8; ++t) {
                int oc = ch * 128 + t * 16 + l15;
                mix[(size_t)rr * OUT_CH + oc] = bfbits(p0 * acc2[rt][t][r]);
            }
        }
}

// ---------- 5. depthwise conv (39 taps) + identity, LDS-staged, 256 threads ----
#define CT2 64                  // t outputs per block
#define CR2 (CT2 + 38)          // 102 staged rows
__global__ __launch_bounds__(256, 2) void conv_kernel(
    const unsigned short* __restrict__ mix,
    const float* __restrict__ conv_w,   // [256][1][39]
    float* __restrict__ out) {
    __shared__ __align__(16) unsigned short lds[CR2 * 256];   // 51 KB

    const int tid = threadIdx.x;
    const int blk = blockIdx.x;
    const int b   = blk / 63;
    const int t0  = (blk % 63) * CT2;

    // ---- stage: 102*256/8 = 3264 u16x8 chunks, 256 threads ----
#pragma unroll
    for (int it = 0; it < 13; ++it) {
        int chunk = it * 256 + tid;
        if (it == 12 && tid >= 192) break;
        int e = chunk * 8;
        int s = e >> 8, c = e & 255;
        int t = t0 - 19 + s;
        u16x8 o;
        if (t >= 0 && t < NT) {
            o = *reinterpret_cast<const u16x8*>(&mix[((size_t)b * NT + t) * OUT_CH + c]);
        } else {
#pragma unroll
            for (int k = 0; k < 8; ++k) o[k] = 0;
        }
        *reinterpret_cast<u16x8*>(&lds[s * 256 + c]) = o;
    }
    __syncthreads();

    const int c = tid;
    float cw[39];
#pragma unroll
    for (int j = 0; j < 39; ++j) cw[j] = conv_w[c * 39 + j];

#pragma unroll 1
    for (int g = 0; g < 4; ++g) {
        const int u0 = g * 16;   // row offset in tile
        float vwin[54];
#pragma unroll
        for (int i = 0; i < 54; ++i)
            vwin[i] = bf2f(lds[(u0 + i) * 256 + c]);
        float acc[16];
#pragma unroll
        for (int o = 0; o < 16; ++o) {
            float a = vwin[o + 19];          // identity (xp + conv)
#pragma unroll
            for (int j = 0; j < 39; ++j)
                a += cw[j] * vwin[o + j];
            acc[o] = a;
        }
        const int tbase = t0 + u0;
#pragma unroll
        for (int o = 0; o < 16; ++o) {
            int t = tbase + o;
            if (t < NT)
                out[((size_t)b * NT + t) * OUT_CH + c] = acc[o];
        }
    }
}

// ---------- launch ----------
extern "C" void kernel_launch(void* const* d_in, const int* in_sizes, int n_in,
                              void* d_out, int out_size, void* d_ws, size_t ws_size,
                              hipStream_t stream) {
    const float* x      = (const float*)d_in[0];
    const float* w1     = (const float*)d_in[1];
    const float* b1     = (const float*)d_in[2];
    const float* w2     = (const float*)d_in[3];
    const float* conv_w = (const float*)d_in[4];
    const float* gate_w = (const float*)d_in[5];
    const float* gate_b = (const float*)d_in[6];
    const float* tau    = (const float*)d_in[7];
    float* out = (float*)d_out;

    char* ws = (char*)d_ws;
    unsigned short* w1b = (unsigned short*)(ws);
    unsigned short* w2b = (unsigned short*)(ws + 1048576);
    unsigned short* mix = (unsigned short*)(ws + 2097152);
    float* psum  = (float*)(ws + 2097152 + 2 * 16384000);
    float* psq   = psum + 256 * 256;
    float* probs = psq + 256 * 256;

    cvt_kernel<<<dim3(1024), dim3(256), 0, stream>>>(w1, w1b, w2, w2b);
    reduce_kernel<<<dim3(256), dim3(256), 0, stream>>>(x, psum, psq);
    gate_kernel<<<dim3(1), dim3(256), 0, stream>>>(psum, psq, gate_w, gate_b, tau,
                                                   probs, out + 8192000);
    gemm_kernel<<<dim3(500), dim3(256), 0, stream>>>(x, w1b, w2b, b1, probs, mix);
    conv_kernel<<<dim3(504), dim3(256), 0, stream>>>(mix, conv_w, out);
}

// Round 14
// 186.167 us; speedup vs baseline: 1.1784x; 1.1784x over previous
//
#include <hip/hip_runtime.h>

// ---------- types ----------
typedef __bf16 bf16x8 __attribute__((ext_vector_type(8)));
typedef float  f32x4  __attribute__((ext_vector_type(4)));
typedef unsigned short u16x8 __attribute__((ext_vector_type(8)));

#define IN_CH  256
#define OUT_CH 256
#define HIDDEN 2048
#define NB     8
#define NT     4000
#define NROW   32000   // NB*NT
#define F1LD   66      // f1t leading dim (odd word stride -> spread banks)

__device__ __forceinline__ unsigned short bfbits(float f) {
    __bf16 h = (__bf16)f;                       // native cvt (RTNE)
    return *reinterpret_cast<unsigned short*>(&h);
}
__device__ __forceinline__ float bf2f(unsigned short h) {
    return __uint_as_float(((unsigned)h) << 16);
}

#define GLOAD_LDS16(g, l) \
    __builtin_amdgcn_global_load_lds((const __attribute__((address_space(1))) void*)(g), \
                                     (__attribute__((address_space(3))) void*)(l), 16, 0, 0)

// ---------- 1. prep: cvt (blocks 0..1023) + reduce (1024..1279) + gate (last) ----
// Fuses 3 launches into 1. Gate runs in the LAST reduce block to finish
// (fence + device-scope atomic counter, zeroed via hipMemsetAsync each call).
__global__ __launch_bounds__(256) void prep_kernel(
    const float* __restrict__ w1, unsigned short* __restrict__ w1o,
    const float* __restrict__ w2, unsigned short* __restrict__ w2o,
    const float* __restrict__ x, float* __restrict__ psum, float* __restrict__ psq,
    const float* __restrict__ gate_w, const float* __restrict__ gate_b,
    const float* __restrict__ tau, float* __restrict__ probs,
    float* __restrict__ losses, unsigned* __restrict__ counter) {
    const int tid = threadIdx.x;
    const int blk = blockIdx.x;

    if (blk < 1024) {          // ---- cvt: 262144 float4 chunks over w1,w2 ----
        int i = blk * 256 + tid;
        const float* in; unsigned short* outp; int j;
        if (i < 131072) { in = w1; outp = w1o; j = i; }
        else            { in = w2; outp = w2o; j = i - 131072; }
        float4 v = reinterpret_cast<const float4*>(in)[j];
        ushort4 o;
        o.x = bfbits(v.x); o.y = bfbits(v.y); o.z = bfbits(v.z); o.w = bfbits(v.w);
        reinterpret_cast<ushort4*>(outp)[j] = o;
        return;
    }

    // ---- reduce: partial mean/var over 125 rows ----
    const int rblk = blk - 1024;          // 0..255
    const int b = rblk >> 5, tc = rblk & 31;
    {
        const float* base = x + ((size_t)b * NT + tc * 125) * IN_CH + tid;
        float s = 0.f, q = 0.f;
        for (int t = 0; t < 125; ++t) {
            float v = base[(size_t)t * IN_CH];
            s += v; q += v * v;
        }
        psum[rblk * IN_CH + tid] = s;
        psq [rblk * IN_CH + tid] = q;
    }
    __threadfence();                      // release partials (device scope)
    __syncthreads();
    __shared__ int last;
    if (tid == 0) last = (atomicAdd(counter, 1u) == 255u);
    __syncthreads();
    if (!last) return;
    __threadfence();                      // acquire all partials

    // ---- gate (one block, 256 threads) ----
    __shared__ float gi[NB][2 * IN_CH];
    __shared__ float lgt[16];
    for (int bb = 0; bb < NB; ++bb) {
        float s = 0.f, q = 0.f;
        for (int p = 0; p < 32; ++p) {
            s += psum[(bb * 32 + p) * IN_CH + tid];
            q += psq [(bb * 32 + p) * IN_CH + tid];
        }
        float mean = s * (1.f / 4000.f);
        float var  = (q - s * s * (1.f / 4000.f)) * (1.f / 3999.f);  // ddof=1
        gi[bb][tid]         = mean;
        gi[bb][IN_CH + tid] = sqrtf(fmaxf(var, 0.f));
    }
    __syncthreads();
    if (tid < 16) {
        int bb = tid >> 1, k = tid & 1;
        float d = 0.f;
        for (int i = 0; i < 2 * IN_CH; ++i) d += gi[bb][i] * gate_w[k * 2 * IN_CH + i];
        lgt[tid] = tau[0] * (d + gate_b[k]);
    }
    __syncthreads();
    if (tid == 0) {
        float pr[16];
        float i0 = 0.f, i1 = 0.f, sp = 0.f;
        for (int bb = 0; bb < NB; ++bb) {
            float a = lgt[bb * 2], c2 = lgt[bb * 2 + 1];
            float mx = fmaxf(a, c2);
            float e0 = expf(a - mx), e1 = expf(c2 - mx);
            float inv = 1.f / (e0 + e1);
            float q0 = e0 * inv, q1 = e1 * inv;
            pr[bb * 2] = q0; pr[bb * 2 + 1] = q1;
            i0 += q0; i1 += q1;
            float nrm = sqrtf(q0 * q0 + q1 * q1) + 1e-8f;
            sp += (q0 + q1) / nrm;
        }
        losses[0] = 0.1f * sp * (1.f / 8.f);
        i0 *= (1.f / 8.f); i1 *= (1.f / 8.f);
        float meanI = 0.5f * (i0 + i1);
        float stdI  = fabsf(i0 - i1) * 0.7071067811865476f;
        float cv = stdI / (meanI + 1e-8f);
        losses[1] = 0.01f * cv * cv;
        for (int t = 0; t < 16; ++t) probs[t] = pr[t];
    }
}

// ---------- 2. fused GEMM1(relu)+GEMM2 -> mixed output (R12 structure) ----
// 500 blocks x 256 threads (4 waves = 2 rb x 2 ch), BK=64, 3 barriers/chunk,
// w1+w2 staged in LDS (74 KB, 2 blocks/CU anti-phased), 128 VGPR + 80 AGPR
// -> 2 waves/SIMD. R13's BK=32 + w2-from-global regressed (157us): per-barrier
// MFMA cluster too thin to cover the vmcnt(0) drain of global-latency loads.
// NEW vs R12: s_setprio(1) around MFMA clusters -- the 2 co-resident blocks
// are anti-phased (one stages while the other computes), giving the wave-role
// diversity T5 needs (null in lockstep m190, +34% with role split m224).
__global__ __launch_bounds__(256, 2) void gemm_kernel(
    const float* __restrict__ x,
    const unsigned short* __restrict__ w1b,   // [2048][256] bf16
    const unsigned short* __restrict__ w2b,   // [256][2048] bf16
    const float* __restrict__ b1,
    const float* __restrict__ probs,          // [8][2]
    unsigned short* __restrict__ mix) {       // [32000][256] bf16 (pre-mixed)
    __shared__ __align__(16) unsigned short w1c[64 * 256];   // 32 KB
    __shared__ __align__(16) unsigned short w2c[256 * 64];   // 32 KB
    __shared__ __align__(16) unsigned short f1t[64 * F1LD];  // 8.25 KB

    const int tid   = threadIdx.x;
    const int lane  = tid & 63;
    const int wv    = tid >> 6;       // 0..3
    const int rb    = wv & 1;         // 32-row band
    const int ch    = wv >> 1;        // 0..1 oc half (128 each)
    const int m0    = blockIdx.x * 64;
    const int l15   = lane & 15;
    const int lg    = lane >> 4;      // 0..3

    bf16x8 xr[2][8];
#pragma unroll
    for (int rt = 0; rt < 2; ++rt) {
        const float* xrow = x + (size_t)(m0 + rb * 32 + rt * 16 + l15) * IN_CH;
#pragma unroll
        for (int kk = 0; kk < 8; ++kk) {
            float4 v0 = *reinterpret_cast<const float4*>(xrow + kk * 32 + lg * 8);
            float4 v1 = *reinterpret_cast<const float4*>(xrow + kk * 32 + lg * 8 + 4);
            bf16x8 h;
            h[0] = (__bf16)v0.x; h[1] = (__bf16)v0.y; h[2] = (__bf16)v0.z; h[3] = (__bf16)v0.w;
            h[4] = (__bf16)v1.x; h[5] = (__bf16)v1.y; h[6] = (__bf16)v1.z; h[7] = (__bf16)v1.w;
            xr[rt][kk] = h;
        }
    }

    f32x4 acc2[2][8];
#pragma unroll
    for (int rt = 0; rt < 2; ++rt)
#pragma unroll
        for (int t = 0; t < 8; ++t) { acc2[rt][t][0]=0.f; acc2[rt][t][1]=0.f; acc2[rt][t][2]=0.f; acc2[rt][t][3]=0.f; }

#pragma unroll 1
    for (int chunk = 0; chunk < 32; ++chunk) {
        {
            const int h0 = chunk * 64;
            const unsigned short* w1s = w1b + (size_t)h0 * IN_CH;
            const unsigned short* w2s = w2b + h0;
#pragma unroll
            for (int i = 0; i < 8; ++i) {
                int seg = i * 4 + wv;                       // 0..31
                int r1 = seg * 2 + (lane >> 5);
                int c1 = ((lane & 31) * 8) ^ ((r1 & 7) << 3);
                GLOAD_LDS16(w1s + r1 * 256 + c1, &w1c[seg * 512]);
                int r2 = seg * 8 + (lane >> 3);
                int c2 = ((lane & 7) * 8) ^ ((r2 & 7) << 3);
                GLOAD_LDS16(w2s + (size_t)r2 * HIDDEN + c2, &w2c[seg * 512]);
            }
        }

        __syncthreads();   // [A] vmcnt drained -> weights ready

        f32x4 acc1[2][2];
#pragma unroll
        for (int rt = 0; rt < 2; ++rt)
#pragma unroll
            for (int ht = 0; ht < 2; ++ht) { acc1[rt][ht][0]=0.f; acc1[rt][ht][1]=0.f; acc1[rt][ht][2]=0.f; acc1[rt][ht][3]=0.f; }
        __builtin_amdgcn_s_setprio(1);
#pragma unroll
        for (int kk = 0; kk < 8; ++kk) {
            const int kE = kk * 32 + lg * 8;
            bf16x8 bb[2];
#pragma unroll
            for (int ht = 0; ht < 2; ++ht) {
                const int hl = ch * 32 + ht * 16 + l15;
                bb[ht] = *reinterpret_cast<const bf16x8*>(
                    &w1c[hl * 256 + (kE ^ ((hl & 7) << 3))]);
            }
#pragma unroll
            for (int rt = 0; rt < 2; ++rt)
#pragma unroll
                for (int ht = 0; ht < 2; ++ht)
                    acc1[rt][ht] = __builtin_amdgcn_mfma_f32_16x16x32_bf16(
                        xr[rt][kk], bb[ht], acc1[rt][ht], 0, 0, 0);
        }
        __builtin_amdgcn_s_setprio(0);
#pragma unroll
        for (int ht = 0; ht < 2; ++ht) {
            const int hl = ch * 32 + ht * 16 + l15;
            const float bias = b1[chunk * 64 + hl];   // L2-hit scalar
#pragma unroll
            for (int rt = 0; rt < 2; ++rt)
#pragma unroll
                for (int r = 0; r < 4; ++r) {
                    float v = fmaxf(acc1[rt][ht][r] + bias, 0.f);
                    int rr = rb * 32 + rt * 16 + lg * 4 + r;
                    f1t[rr * F1LD + hl] = bfbits(v);
                }
        }

        __syncthreads();   // [B] f1t ready

        __builtin_amdgcn_s_setprio(1);
#pragma unroll
        for (int kk = 0; kk < 2; ++kk) {
            const int kE = kk * 32 + lg * 8;
            bf16x8 a2[2];
#pragma unroll
            for (int rt = 0; rt < 2; ++rt)
                a2[rt] = *reinterpret_cast<const bf16x8*>(
                    &f1t[(rb * 32 + rt * 16 + l15) * F1LD + kE]);
#pragma unroll
            for (int t = 0; t < 8; ++t) {
                int oc = ch * 128 + t * 16 + l15;
                bf16x8 b2 = *reinterpret_cast<const bf16x8*>(
                    &w2c[oc * 64 + (kE ^ ((oc & 7) << 3))]);
#pragma unroll
                for (int rt = 0; rt < 2; ++rt)
                    acc2[rt][t] = __builtin_amdgcn_mfma_f32_16x16x32_bf16(
                        a2[rt], b2, acc2[rt][t], 0, 0, 0);
            }
        }
        __builtin_amdgcn_s_setprio(0);

        if (chunk == 3) {   // small branch done: rescale so p0*acc2 = p0*full+p1*small
#pragma unroll
            for (int rt = 0; rt < 2; ++rt)
#pragma unroll
                for (int r = 0; r < 4; ++r) {
                    int rr = m0 + rb * 32 + rt * 16 + lg * 4 + r;
                    int bb = rr / 4000;
                    float p0 = probs[bb * 2], p1 = probs[bb * 2 + 1];
                    float ratio = (p0 + p1) / fmaxf(p0, 1e-30f);
#pragma unroll
                    for (int t = 0; t < 8; ++t)
                        acc2[rt][t][r] *= ratio;
                }
        }

        __syncthreads();   // [C] reads done -> next stage may overwrite
    }
    // final: mix = p0 * acc2 (= p0*full + p1*small)
#pragma unroll
    for (int rt = 0; rt < 2; ++rt)
#pragma unroll
        for (int r = 0; r < 4; ++r) {
            int rr = m0 + rb * 32 + rt * 16 + lg * 4 + r;
            int bb = rr / 4000;
            float p0 = probs[bb * 2];
#pragma unroll
            for (int t = 0; t < 8; ++t) {
                int oc = ch * 128 + t * 16 + l15;
                mix[(size_t)rr * OUT_CH + oc] = bfbits(p0 * acc2[rt][t][r]);
            }
        }
}

// ---------- 3. depthwise conv (39 taps) + identity, LDS-staged, 256 threads ----
#define CT2 64                  // t outputs per block
#define CR2 (CT2 + 38)          // 102 staged rows
__global__ __launch_bounds__(256, 2) void conv_kernel(
    const unsigned short* __restrict__ mix,
    const float* __restrict__ conv_w,   // [256][1][39]
    float* __restrict__ out) {
    __shared__ __align__(16) unsigned short lds[CR2 * 256];   // 51 KB

    const int tid = threadIdx.x;
    const int blk = blockIdx.x;
    const int b   = blk / 63;
    const int t0  = (blk % 63) * CT2;

#pragma unroll
    for (int it = 0; it < 13; ++it) {
        int chunk = it * 256 + tid;
        if (it == 12 && tid >= 192) break;
        int e = chunk * 8;
        int s = e >> 8, c = e & 255;
        int t = t0 - 19 + s;
        u16x8 o;
        if (t >= 0 && t < NT) {
            o = *reinterpret_cast<const u16x8*>(&mix[((size_t)b * NT + t) * OUT_CH + c]);
        } else {
#pragma unroll
            for (int k = 0; k < 8; ++k) o[k] = 0;
        }
        *reinterpret_cast<u16x8*>(&lds[s * 256 + c]) = o;
    }
    __syncthreads();

    const int c = tid;
    float cw[39];
#pragma unroll
    for (int j = 0; j < 39; ++j) cw[j] = conv_w[c * 39 + j];

#pragma unroll 1
    for (int g = 0; g < 4; ++g) {
        const int u0 = g * 16;
        float vwin[54];
#pragma unroll
        for (int i = 0; i < 54; ++i)
            vwin[i] = bf2f(lds[(u0 + i) * 256 + c]);
        float acc[16];
#pragma unroll
        for (int o = 0; o < 16; ++o) {
            float a = vwin[o + 19];          // identity (xp + conv)
#pragma unroll
            for (int j = 0; j < 39; ++j)
                a += cw[j] * vwin[o + j];
            acc[o] = a;
        }
        const int tbase = t0 + u0;
#pragma unroll
        for (int o = 0; o < 16; ++o) {
            int t = tbase + o;
            if (t < NT)
                out[((size_t)b * NT + t) * OUT_CH + c] = acc[o];
        }
    }
}

// ---------- launch ----------
extern "C" void kernel_launch(void* const* d_in, const int* in_sizes, int n_in,
                              void* d_out, int out_size, void* d_ws, size_t ws_size,
                              hipStream_t stream) {
    const float* x      = (const float*)d_in[0];
    const float* w1     = (const float*)d_in[1];
    const float* b1     = (const float*)d_in[2];
    const float* w2     = (const float*)d_in[3];
    const float* conv_w = (const float*)d_in[4];
    const float* gate_w = (const float*)d_in[5];
    const float* gate_b = (const float*)d_in[6];
    const float* tau    = (const float*)d_in[7];
    float* out = (float*)d_out;

    char* ws = (char*)d_ws;
    unsigned short* w1b = (unsigned short*)(ws);
    unsigned short* w2b = (unsigned short*)(ws + 1048576);
    unsigned short* mix = (unsigned short*)(ws + 2097152);
    float* psum  = (float*)(ws + 2097152 + 2 * 16384000);
    float* psq   = psum + 256 * 256;
    float* probs = psq + 256 * 256;
    unsigned* counter = (unsigned*)(probs + 16);

    hipMemsetAsync(counter, 0, 4, stream);
    prep_kernel<<<dim3(1280), dim3(256), 0, stream>>>(
        w1, w1b, w2, w2b, x, psum, psq, gate_w, gate_b, tau,
        probs, out + 8192000, counter);
    gemm_kernel<<<dim3(500), dim3(256), 0, stream>>>(x, w1b, w2b, b1, probs, mix);
    conv_kernel<<<dim3(504), dim3(256), 0, stream>>>(mix, conv_w, out);
}

// Round 15
// 165.451 us; speedup vs baseline: 1.3260x; 1.1252x over previous
//
#include <hip/hip_runtime.h>

// ---------- types ----------
typedef __bf16 bf16x8 __attribute__((ext_vector_type(8)));
typedef float  f32x4  __attribute__((ext_vector_type(4)));
typedef unsigned short u16x8 __attribute__((ext_vector_type(8)));

#define IN_CH  256
#define OUT_CH 256
#define HIDDEN 2048
#define NB     8
#define NT     4000
#define NROW   32000   // NB*NT
#define F1LD   70      // f1t row stride: 35 dwords -> a2 banks (3*l15+4*lg), <=2-way
                       // (66 gave (l15+4lg): 4-way, 8.19M conflicts; 72 gives 8-way)

__device__ __forceinline__ unsigned short bfbits(float f) {
    __bf16 h = (__bf16)f;                       // native cvt (RTNE)
    return *reinterpret_cast<unsigned short*>(&h);
}
__device__ __forceinline__ float bf2f(unsigned short h) {
    return __uint_as_float(((unsigned)h) << 16);
}

#define GLOAD_LDS16(g, l) \
    __builtin_amdgcn_global_load_lds((const __attribute__((address_space(1))) void*)(g), \
                                     (__attribute__((address_space(3))) void*)(l), 16, 0, 0)

// ---------- 1. fp32 -> bf16 convert (both weight tensors, one launch) ----------
__global__ void cvt_kernel(const float* __restrict__ w1,
                           unsigned short* __restrict__ w1o,
                           const float* __restrict__ w2,
                           unsigned short* __restrict__ w2o) {
    int i = blockIdx.x * blockDim.x + threadIdx.x;   // 0..262143
    const float* in;
    unsigned short* outp;
    int j;
    if (i < 131072) { in = w1; outp = w1o; j = i; }
    else            { in = w2; outp = w2o; j = i - 131072; }
    float4 v = reinterpret_cast<const float4*>(in)[j];
    ushort4 o;
    o.x = bfbits(v.x); o.y = bfbits(v.y); o.z = bfbits(v.z); o.w = bfbits(v.w);
    reinterpret_cast<ushort4*>(outp)[j] = o;
}

// ---------- 2. partial mean/var reduction over T ----------
__global__ void reduce_kernel(const float* __restrict__ x,
                              float* __restrict__ psum, float* __restrict__ psq) {
    int c = threadIdx.x;
    int blk = blockIdx.x;
    int b = blk >> 5, tc = blk & 31;
    const float* base = x + ((size_t)b * NT + tc * 125) * IN_CH + c;
    float s = 0.f, q = 0.f;
    for (int t = 0; t < 125; ++t) {
        float v = base[(size_t)t * IN_CH];
        s += v; q += v * v;
    }
    psum[blk * IN_CH + c] = s;
    psq [blk * IN_CH + c] = q;
}

// ---------- 3. gate: mean/std -> logits -> probs -> losses ----------
__global__ __launch_bounds__(256) void gate_kernel(
    const float* __restrict__ psum, const float* __restrict__ psq,
    const float* __restrict__ gate_w, const float* __restrict__ gate_b,
    const float* __restrict__ tau, float* __restrict__ probs,
    float* __restrict__ losses) {
    __shared__ float gi[NB][2 * IN_CH];
    __shared__ float lgt[16];
    int tid = threadIdx.x;
    for (int b = 0; b < NB; ++b) {
        float s = 0.f, q = 0.f;
        for (int p = 0; p < 32; ++p) {
            s += psum[(b * 32 + p) * IN_CH + tid];
            q += psq [(b * 32 + p) * IN_CH + tid];
        }
        float mean = s * (1.f / 4000.f);
        float var  = (q - s * s * (1.f / 4000.f)) * (1.f / 3999.f);  // ddof=1
        gi[b][tid]          = mean;
        gi[b][IN_CH + tid]  = sqrtf(fmaxf(var, 0.f));
    }
    __syncthreads();
    if (tid < 16) {
        int b = tid >> 1, k = tid & 1;
        float d = 0.f;
        for (int i = 0; i < 2 * IN_CH; ++i) d += gi[b][i] * gate_w[k * 2 * IN_CH + i];
        lgt[tid] = tau[0] * (d + gate_b[k]);
    }
    __syncthreads();
    if (tid == 0) {
        float pr[16];
        float i0 = 0.f, i1 = 0.f, sp = 0.f;
        for (int b = 0; b < NB; ++b) {
            float a = lgt[b * 2], c2 = lgt[b * 2 + 1];
            float mx = fmaxf(a, c2);
            float e0 = expf(a - mx), e1 = expf(c2 - mx);
            float inv = 1.f / (e0 + e1);
            float q0 = e0 * inv, q1 = e1 * inv;
            pr[b * 2] = q0; pr[b * 2 + 1] = q1;
            i0 += q0; i1 += q1;
            float nrm = sqrtf(q0 * q0 + q1 * q1) + 1e-8f;
            sp += (q0 + q1) / nrm;
        }
        losses[0] = 0.1f * sp * (1.f / 8.f);
        i0 *= (1.f / 8.f); i1 *= (1.f / 8.f);
        float meanI = 0.5f * (i0 + i1);
        float stdI  = fabsf(i0 - i1) * 0.7071067811865476f;
        float cv = stdI / (meanI + 1e-8f);
        losses[1] = 0.01f * cv * cv;
        for (int t = 0; t < 16; ++t) probs[t] = pr[t];
    }
}

// ---------- 4. fused GEMM1(relu)+GEMM2 -> mixed output (R12 structure) ----
// 500 blocks x 256 threads (4 waves = 2 rb x 2 ch), BK=64, 3 barriers/chunk,
// w1+w2 staged in LDS (74 KB, 2 blocks/CU anti-phased), 128 VGPR + 80 AGPR
// -> 2 waves/SIMD. Best measured config (R12: 97.9us). R13 BK=32 regressed
// (thin MFMA clusters); R14 setprio neutral -> dropped. This round: F1LD 66->70
// to cut the a2/f1t 4-way bank conflicts (8.19M -> expect <5M).
__global__ __launch_bounds__(256, 2) void gemm_kernel(
    const float* __restrict__ x,
    const unsigned short* __restrict__ w1b,   // [2048][256] bf16
    const unsigned short* __restrict__ w2b,   // [256][2048] bf16
    const float* __restrict__ b1,
    const float* __restrict__ probs,          // [8][2]
    unsigned short* __restrict__ mix) {       // [32000][256] bf16 (pre-mixed)
    __shared__ __align__(16) unsigned short w1c[64 * 256];   // 32 KB
    __shared__ __align__(16) unsigned short w2c[256 * 64];   // 32 KB
    __shared__ __align__(16) unsigned short f1t[64 * F1LD];  // 8.75 KB

    const int tid   = threadIdx.x;
    const int lane  = tid & 63;
    const int wv    = tid >> 6;       // 0..3
    const int rb    = wv & 1;         // 32-row band
    const int ch    = wv >> 1;        // 0..1 oc half (128 each)
    const int m0    = blockIdx.x * 64;
    const int l15   = lane & 15;
    const int lg    = lane >> 4;      // 0..3

    bf16x8 xr[2][8];
#pragma unroll
    for (int rt = 0; rt < 2; ++rt) {
        const float* xrow = x + (size_t)(m0 + rb * 32 + rt * 16 + l15) * IN_CH;
#pragma unroll
        for (int kk = 0; kk < 8; ++kk) {
            float4 v0 = *reinterpret_cast<const float4*>(xrow + kk * 32 + lg * 8);
            float4 v1 = *reinterpret_cast<const float4*>(xrow + kk * 32 + lg * 8 + 4);
            bf16x8 h;
            h[0] = (__bf16)v0.x; h[1] = (__bf16)v0.y; h[2] = (__bf16)v0.z; h[3] = (__bf16)v0.w;
            h[4] = (__bf16)v1.x; h[5] = (__bf16)v1.y; h[6] = (__bf16)v1.z; h[7] = (__bf16)v1.w;
            xr[rt][kk] = h;
        }
    }

    f32x4 acc2[2][8];
#pragma unroll
    for (int rt = 0; rt < 2; ++rt)
#pragma unroll
        for (int t = 0; t < 8; ++t) { acc2[rt][t][0]=0.f; acc2[rt][t][1]=0.f; acc2[rt][t][2]=0.f; acc2[rt][t][3]=0.f; }

#pragma unroll 1
    for (int chunk = 0; chunk < 32; ++chunk) {
        {
            const int h0 = chunk * 64;
            const unsigned short* w1s = w1b + (size_t)h0 * IN_CH;
            const unsigned short* w2s = w2b + h0;
#pragma unroll
            for (int i = 0; i < 8; ++i) {
                int seg = i * 4 + wv;                       // 0..31
                int r1 = seg * 2 + (lane >> 5);
                int c1 = ((lane & 31) * 8) ^ ((r1 & 7) << 3);
                GLOAD_LDS16(w1s + r1 * 256 + c1, &w1c[seg * 512]);
                int r2 = seg * 8 + (lane >> 3);
                int c2 = ((lane & 7) * 8) ^ ((r2 & 7) << 3);
                GLOAD_LDS16(w2s + (size_t)r2 * HIDDEN + c2, &w2c[seg * 512]);
            }
        }

        __syncthreads();   // [A] vmcnt drained -> weights ready

        f32x4 acc1[2][2];
#pragma unroll
        for (int rt = 0; rt < 2; ++rt)
#pragma unroll
            for (int ht = 0; ht < 2; ++ht) { acc1[rt][ht][0]=0.f; acc1[rt][ht][1]=0.f; acc1[rt][ht][2]=0.f; acc1[rt][ht][3]=0.f; }
#pragma unroll
        for (int kk = 0; kk < 8; ++kk) {
            const int kE = kk * 32 + lg * 8;
            bf16x8 bb[2];
#pragma unroll
            for (int ht = 0; ht < 2; ++ht) {
                const int hl = ch * 32 + ht * 16 + l15;
                bb[ht] = *reinterpret_cast<const bf16x8*>(
                    &w1c[hl * 256 + (kE ^ ((hl & 7) << 3))]);
            }
#pragma unroll
            for (int rt = 0; rt < 2; ++rt)
#pragma unroll
                for (int ht = 0; ht < 2; ++ht)
                    acc1[rt][ht] = __builtin_amdgcn_mfma_f32_16x16x32_bf16(
                        xr[rt][kk], bb[ht], acc1[rt][ht], 0, 0, 0);
        }
#pragma unroll
        for (int ht = 0; ht < 2; ++ht) {
            const int hl = ch * 32 + ht * 16 + l15;
            const float bias = b1[chunk * 64 + hl];   // L2-hit scalar
#pragma unroll
            for (int rt = 0; rt < 2; ++rt)
#pragma unroll
                for (int r = 0; r < 4; ++r) {
                    float v = fmaxf(acc1[rt][ht][r] + bias, 0.f);
                    int rr = rb * 32 + rt * 16 + lg * 4 + r;
                    f1t[rr * F1LD + hl] = bfbits(v);
                }
        }

        __syncthreads();   // [B] f1t ready

#pragma unroll
        for (int kk = 0; kk < 2; ++kk) {
            const int kE = kk * 32 + lg * 8;
            bf16x8 a2[2];
#pragma unroll
            for (int rt = 0; rt < 2; ++rt)
                a2[rt] = *reinterpret_cast<const bf16x8*>(
                    &f1t[(rb * 32 + rt * 16 + l15) * F1LD + kE]);
#pragma unroll
            for (int t = 0; t < 8; ++t) {
                int oc = ch * 128 + t * 16 + l15;
                bf16x8 b2 = *reinterpret_cast<const bf16x8*>(
                    &w2c[oc * 64 + (kE ^ ((oc & 7) << 3))]);
#pragma unroll
                for (int rt = 0; rt < 2; ++rt)
                    acc2[rt][t] = __builtin_amdgcn_mfma_f32_16x16x32_bf16(
                        a2[rt], b2, acc2[rt][t], 0, 0, 0);
            }
        }

        if (chunk == 3) {   // small branch done: rescale so p0*acc2 = p0*full+p1*small
#pragma unroll
            for (int rt = 0; rt < 2; ++rt)
#pragma unroll
                for (int r = 0; r < 4; ++r) {
                    int rr = m0 + rb * 32 + rt * 16 + lg * 4 + r;
                    int bb = rr / 4000;
                    float p0 = probs[bb * 2], p1 = probs[bb * 2 + 1];
                    float ratio = (p0 + p1) / fmaxf(p0, 1e-30f);
#pragma unroll
                    for (int t = 0; t < 8; ++t)
                        acc2[rt][t][r] *= ratio;
                }
        }

        __syncthreads();   // [C] reads done -> next stage may overwrite
    }
    // final: mix = p0 * acc2 (= p0*full + p1*small)
#pragma unroll
    for (int rt = 0; rt < 2; ++rt)
#pragma unroll
        for (int r = 0; r < 4; ++r) {
            int rr = m0 + rb * 32 + rt * 16 + lg * 4 + r;
            int bb = rr / 4000;
            float p0 = probs[bb * 2];
#pragma unroll
            for (int t = 0; t < 8; ++t) {
                int oc = ch * 128 + t * 16 + l15;
                mix[(size_t)rr * OUT_CH + oc] = bfbits(p0 * acc2[rt][t][r]);
            }
        }
}

// ---------- 5. depthwise conv (39 taps) + identity, LDS-staged, 256 threads ----
#define CT2 64                  // t outputs per block
#define CR2 (CT2 + 38)          // 102 staged rows
__global__ __launch_bounds__(256, 2) void conv_kernel(
    const unsigned short* __restrict__ mix,
    const float* __restrict__ conv_w,   // [256][1][39]
    float* __restrict__ out) {
    __shared__ __align__(16) unsigned short lds[CR2 * 256];   // 51 KB

    const int tid = threadIdx.x;
    const int blk = blockIdx.x;
    const int b   = blk / 63;
    const int t0  = (blk % 63) * CT2;

#pragma unroll
    for (int it = 0; it < 13; ++it) {
        int chunk = it * 256 + tid;
        if (it == 12 && tid >= 192) break;
        int e = chunk * 8;
        int s = e >> 8, c = e & 255;
        int t = t0 - 19 + s;
        u16x8 o;
        if (t >= 0 && t < NT) {
            o = *reinterpret_cast<const u16x8*>(&mix[((size_t)b * NT + t) * OUT_CH + c]);
        } else {
#pragma unroll
            for (int k = 0; k < 8; ++k) o[k] = 0;
        }
        *reinterpret_cast<u16x8*>(&lds[s * 256 + c]) = o;
    }
    __syncthreads();

    const int c = tid;
    float cw[39];
#pragma unroll
    for (int j = 0; j < 39; ++j) cw[j] = conv_w[c * 39 + j];

#pragma unroll 1
    for (int g = 0; g < 4; ++g) {
        const int u0 = g * 16;
        float vwin[54];
#pragma unroll
        for (int i = 0; i < 54; ++i)
            vwin[i] = bf2f(lds[(u0 + i) * 256 + c]);
        float acc[16];
#pragma unroll
        for (int o = 0; o < 16; ++o) {
            float a = vwin[o + 19];          // identity (xp + conv)
#pragma unroll
            for (int j = 0; j < 39; ++j)
                a += cw[j] * vwin[o + j];
            acc[o] = a;
        }
        const int tbase = t0 + u0;
#pragma unroll
        for (int o = 0; o < 16; ++o) {
            int t = tbase + o;
            if (t < NT)
                out[((size_t)b * NT + t) * OUT_CH + c] = acc[o];
        }
    }
}

// ---------- launch ----------
extern "C" void kernel_launch(void* const* d_in, const int* in_sizes, int n_in,
                              void* d_out, int out_size, void* d_ws, size_t ws_size,
                              hipStream_t stream) {
    const float* x      = (const float*)d_in[0];
    const float* w1     = (const float*)d_in[1];
    const float* b1     = (const float*)d_in[2];
    const float* w2     = (const float*)d_in[3];
    const float* conv_w = (const float*)d_in[4];
    const float* gate_w = (const float*)d_in[5];
    const float* gate_b = (const float*)d_in[6];
    const float* tau    = (const float*)d_in[7];
    float* out = (float*)d_out;

    char* ws = (char*)d_ws;
    unsigned short* w1b = (unsigned short*)(ws);
    unsigned short* w2b = (unsigned short*)(ws + 1048576);
    unsigned short* mix = (unsigned short*)(ws + 2097152);
    float* psum  = (float*)(ws + 2097152 + 2 * 16384000);
    float* psq   = psum + 256 * 256;
    float* probs = psq + 256 * 256;

    cvt_kernel<<<dim3(1024), dim3(256), 0, stream>>>(w1, w1b, w2, w2b);
    reduce_kernel<<<dim3(256), dim3(256), 0, stream>>>(x, psum, psq);
    gate_kernel<<<dim3(1), dim3(256), 0, stream>>>(psum, psq, gate_w, gate_b, tau,
                                                   probs, out + 8192000);
    gemm_kernel<<<dim3(500), dim3(256), 0, stream>>>(x, w1b, w2b, b1, probs, mix);
    conv_kernel<<<dim3(504), dim3(256), 0, stream>>>(mix, conv_w, out);
}

// Round 16
// 159.242 us; speedup vs baseline: 1.3777x; 1.0390x over previous
//
#include <hip/hip_runtime.h>

// ---------- types ----------
typedef __bf16 bf16x8 __attribute__((ext_vector_type(8)));
typedef float  f32x4  __attribute__((ext_vector_type(4)));
typedef unsigned short u16x8 __attribute__((ext_vector_type(8)));

#define IN_CH  256
#define OUT_CH 256
#define HIDDEN 2048
#define NB     8
#define NT     4000
#define NROW   32000   // NB*NT
#define F1LD   70      // f1t row stride: 35 dwords -> a2 banks (3*l15+4*lg), <=2-way

__device__ __forceinline__ unsigned short bfbits(float f) {
    __bf16 h = (__bf16)f;                       // native cvt (RTNE)
    return *reinterpret_cast<unsigned short*>(&h);
}
__device__ __forceinline__ float bf2f(unsigned short h) {
    return __uint_as_float(((unsigned)h) << 16);
}

#define GLOAD_LDS16(g, l) \
    __builtin_amdgcn_global_load_lds((const __attribute__((address_space(1))) void*)(g), \
                                     (__attribute__((address_space(3))) void*)(l), 16, 0, 0)

// ---------- 1. fp32 -> bf16 convert (both weight tensors, one launch) ----------
__global__ void cvt_kernel(const float* __restrict__ w1,
                           unsigned short* __restrict__ w1o,
                           const float* __restrict__ w2,
                           unsigned short* __restrict__ w2o) {
    int i = blockIdx.x * blockDim.x + threadIdx.x;   // 0..262143
    const float* in;
    unsigned short* outp;
    int j;
    if (i < 131072) { in = w1; outp = w1o; j = i; }
    else            { in = w2; outp = w2o; j = i - 131072; }
    float4 v = reinterpret_cast<const float4*>(in)[j];
    ushort4 o;
    o.x = bfbits(v.x); o.y = bfbits(v.y); o.z = bfbits(v.z); o.w = bfbits(v.w);
    reinterpret_cast<ushort4*>(outp)[j] = o;
}

// ---------- 2. partial mean/var reduction over T ----------
__global__ void reduce_kernel(const float* __restrict__ x,
                              float* __restrict__ psum, float* __restrict__ psq) {
    int c = threadIdx.x;
    int blk = blockIdx.x;
    int b = blk >> 5, tc = blk & 31;
    const float* base = x + ((size_t)b * NT + tc * 125) * IN_CH + c;
    float s = 0.f, q = 0.f;
    for (int t = 0; t < 125; ++t) {
        float v = base[(size_t)t * IN_CH];
        s += v; q += v * v;
    }
    psum[blk * IN_CH + c] = s;
    psq [blk * IN_CH + c] = q;
}

// ---------- 3. gate: mean/std -> logits -> probs -> losses ----------
// Phase-2 (16 dot products of length 512) now parallel across all 256
// threads: pair=(b,k)=tid>>4, seg=tid&15 -> 32-elem partial + LDS tree.
__global__ __launch_bounds__(256) void gate_kernel(
    const float* __restrict__ psum, const float* __restrict__ psq,
    const float* __restrict__ gate_w, const float* __restrict__ gate_b,
    const float* __restrict__ tau, float* __restrict__ probs,
    float* __restrict__ losses) {
    __shared__ float gi[NB][2 * IN_CH];
    __shared__ float part[16][17];
    __shared__ float lgt[16];
    int tid = threadIdx.x;
    for (int b = 0; b < NB; ++b) {
        float s = 0.f, q = 0.f;
        for (int p = 0; p < 32; ++p) {
            s += psum[(b * 32 + p) * IN_CH + tid];
            q += psq [(b * 32 + p) * IN_CH + tid];
        }
        float mean = s * (1.f / 4000.f);
        float var  = (q - s * s * (1.f / 4000.f)) * (1.f / 3999.f);  // ddof=1
        gi[b][tid]          = mean;
        gi[b][IN_CH + tid]  = sqrtf(fmaxf(var, 0.f));
    }
    __syncthreads();
    {
        int pair = tid >> 4, seg = tid & 15;     // pair = b*2+k
        int b = pair >> 1, k = pair & 1;
        float d = 0.f;
        for (int i = seg * 32; i < seg * 32 + 32; ++i)
            d += gi[b][i] * gate_w[k * 2 * IN_CH + i];
        part[pair][seg] = d;
    }
    __syncthreads();
    if (tid < 16) {
        float d = 0.f;
        for (int s = 0; s < 16; ++s) d += part[tid][s];
        lgt[tid] = tau[0] * (d + gate_b[tid & 1]);
    }
    __syncthreads();
    if (tid == 0) {
        float pr[16];
        float i0 = 0.f, i1 = 0.f, sp = 0.f;
        for (int b = 0; b < NB; ++b) {
            float a = lgt[b * 2], c2 = lgt[b * 2 + 1];
            float mx = fmaxf(a, c2);
            float e0 = expf(a - mx), e1 = expf(c2 - mx);
            float inv = 1.f / (e0 + e1);
            float q0 = e0 * inv, q1 = e1 * inv;
            pr[b * 2] = q0; pr[b * 2 + 1] = q1;
            i0 += q0; i1 += q1;
            float nrm = sqrtf(q0 * q0 + q1 * q1) + 1e-8f;
            sp += (q0 + q1) / nrm;
        }
        losses[0] = 0.1f * sp * (1.f / 8.f);
        i0 *= (1.f / 8.f); i1 *= (1.f / 8.f);
        float meanI = 0.5f * (i0 + i1);
        float stdI  = fabsf(i0 - i1) * 0.7071067811865476f;
        float cv = stdI / (meanI + 1e-8f);
        losses[1] = 0.01f * cv * cv;
        for (int t = 0; t < 16; ++t) probs[t] = pr[t];
    }
}

// ---------- 4. fused GEMM1(relu)+GEMM2 -> mixed output (frozen: R12/R15) ----
__global__ __launch_bounds__(256, 2) void gemm_kernel(
    const float* __restrict__ x,
    const unsigned short* __restrict__ w1b,   // [2048][256] bf16
    const unsigned short* __restrict__ w2b,   // [256][2048] bf16
    const float* __restrict__ b1,
    const float* __restrict__ probs,          // [8][2]
    unsigned short* __restrict__ mix) {       // [32000][256] bf16 (pre-mixed)
    __shared__ __align__(16) unsigned short w1c[64 * 256];   // 32 KB
    __shared__ __align__(16) unsigned short w2c[256 * 64];   // 32 KB
    __shared__ __align__(16) unsigned short f1t[64 * F1LD];  // 8.75 KB

    const int tid   = threadIdx.x;
    const int lane  = tid & 63;
    const int wv    = tid >> 6;       // 0..3
    const int rb    = wv & 1;         // 32-row band
    const int ch    = wv >> 1;        // 0..1 oc half (128 each)
    const int m0    = blockIdx.x * 64;
    const int l15   = lane & 15;
    const int lg    = lane >> 4;      // 0..3

    bf16x8 xr[2][8];
#pragma unroll
    for (int rt = 0; rt < 2; ++rt) {
        const float* xrow = x + (size_t)(m0 + rb * 32 + rt * 16 + l15) * IN_CH;
#pragma unroll
        for (int kk = 0; kk < 8; ++kk) {
            float4 v0 = *reinterpret_cast<const float4*>(xrow + kk * 32 + lg * 8);
            float4 v1 = *reinterpret_cast<const float4*>(xrow + kk * 32 + lg * 8 + 4);
            bf16x8 h;
            h[0] = (__bf16)v0.x; h[1] = (__bf16)v0.y; h[2] = (__bf16)v0.z; h[3] = (__bf16)v0.w;
            h[4] = (__bf16)v1.x; h[5] = (__bf16)v1.y; h[6] = (__bf16)v1.z; h[7] = (__bf16)v1.w;
            xr[rt][kk] = h;
        }
    }

    f32x4 acc2[2][8];
#pragma unroll
    for (int rt = 0; rt < 2; ++rt)
#pragma unroll
        for (int t = 0; t < 8; ++t) { acc2[rt][t][0]=0.f; acc2[rt][t][1]=0.f; acc2[rt][t][2]=0.f; acc2[rt][t][3]=0.f; }

#pragma unroll 1
    for (int chunk = 0; chunk < 32; ++chunk) {
        {
            const int h0 = chunk * 64;
            const unsigned short* w1s = w1b + (size_t)h0 * IN_CH;
            const unsigned short* w2s = w2b + h0;
#pragma unroll
            for (int i = 0; i < 8; ++i) {
                int seg = i * 4 + wv;                       // 0..31
                int r1 = seg * 2 + (lane >> 5);
                int c1 = ((lane & 31) * 8) ^ ((r1 & 7) << 3);
                GLOAD_LDS16(w1s + r1 * 256 + c1, &w1c[seg * 512]);
                int r2 = seg * 8 + (lane >> 3);
                int c2 = ((lane & 7) * 8) ^ ((r2 & 7) << 3);
                GLOAD_LDS16(w2s + (size_t)r2 * HIDDEN + c2, &w2c[seg * 512]);
            }
        }

        __syncthreads();   // [A] vmcnt drained -> weights ready

        f32x4 acc1[2][2];
#pragma unroll
        for (int rt = 0; rt < 2; ++rt)
#pragma unroll
            for (int ht = 0; ht < 2; ++ht) { acc1[rt][ht][0]=0.f; acc1[rt][ht][1]=0.f; acc1[rt][ht][2]=0.f; acc1[rt][ht][3]=0.f; }
#pragma unroll
        for (int kk = 0; kk < 8; ++kk) {
            const int kE = kk * 32 + lg * 8;
            bf16x8 bb[2];
#pragma unroll
            for (int ht = 0; ht < 2; ++ht) {
                const int hl = ch * 32 + ht * 16 + l15;
                bb[ht] = *reinterpret_cast<const bf16x8*>(
                    &w1c[hl * 256 + (kE ^ ((hl & 7) << 3))]);
            }
#pragma unroll
            for (int rt = 0; rt < 2; ++rt)
#pragma unroll
                for (int ht = 0; ht < 2; ++ht)
                    acc1[rt][ht] = __builtin_amdgcn_mfma_f32_16x16x32_bf16(
                        xr[rt][kk], bb[ht], acc1[rt][ht], 0, 0, 0);
        }
#pragma unroll
        for (int ht = 0; ht < 2; ++ht) {
            const int hl = ch * 32 + ht * 16 + l15;
            const float bias = b1[chunk * 64 + hl];   // L2-hit scalar
#pragma unroll
            for (int rt = 0; rt < 2; ++rt)
#pragma unroll
                for (int r = 0; r < 4; ++r) {
                    float v = fmaxf(acc1[rt][ht][r] + bias, 0.f);
                    int rr = rb * 32 + rt * 16 + lg * 4 + r;
                    f1t[rr * F1LD + hl] = bfbits(v);
                }
        }

        __syncthreads();   // [B] f1t ready

#pragma unroll
        for (int kk = 0; kk < 2; ++kk) {
            const int kE = kk * 32 + lg * 8;
            bf16x8 a2[2];
#pragma unroll
            for (int rt = 0; rt < 2; ++rt)
                a2[rt] = *reinterpret_cast<const bf16x8*>(
                    &f1t[(rb * 32 + rt * 16 + l15) * F1LD + kE]);
#pragma unroll
            for (int t = 0; t < 8; ++t) {
                int oc = ch * 128 + t * 16 + l15;
                bf16x8 b2 = *reinterpret_cast<const bf16x8*>(
                    &w2c[oc * 64 + (kE ^ ((oc & 7) << 3))]);
#pragma unroll
                for (int rt = 0; rt < 2; ++rt)
                    acc2[rt][t] = __builtin_amdgcn_mfma_f32_16x16x32_bf16(
                        a2[rt], b2, acc2[rt][t], 0, 0, 0);
            }
        }

        if (chunk == 3) {   // small branch done: rescale so p0*acc2 = p0*full+p1*small
#pragma unroll
            for (int rt = 0; rt < 2; ++rt)
#pragma unroll
                for (int r = 0; r < 4; ++r) {
                    int rr = m0 + rb * 32 + rt * 16 + lg * 4 + r;
                    int bb = rr / 4000;
                    float p0 = probs[bb * 2], p1 = probs[bb * 2 + 1];
                    float ratio = (p0 + p1) / fmaxf(p0, 1e-30f);
#pragma unroll
                    for (int t = 0; t < 8; ++t)
                        acc2[rt][t][r] *= ratio;
                }
        }

        __syncthreads();   // [C] reads done -> next stage may overwrite
    }
    // final: mix = p0 * acc2 (= p0*full + p1*small)
#pragma unroll
    for (int rt = 0; rt < 2; ++rt)
#pragma unroll
        for (int r = 0; r < 4; ++r) {
            int rr = m0 + rb * 32 + rt * 16 + lg * 4 + r;
            int bb = rr / 4000;
            float p0 = probs[bb * 2];
#pragma unroll
            for (int t = 0; t < 8; ++t) {
                int oc = ch * 128 + t * 16 + l15;
                mix[(size_t)rr * OUT_CH + oc] = bfbits(p0 * acc2[rt][t][r]);
            }
        }
}

// ---------- 5. depthwise conv: window-in-registers (70 reads vs 216) ----------
// Thread = (channel c, 32-t slab). Window loaded ONCE into vwin[70] f32,
// then 4 groups x 8 outputs computed purely from registers (static idx).
// Prior version re-read a 54-row window per 16-out group (216 scalar LDS
// reads/thread) -- suspected ~45-57us latency/issue sink. Tile 32 t:
// LDS 35 KB -> 2 blocks/CU; 1000 blocks; 125*32=4000 -> no store bounds.
#define CT3 32                  // t outputs per block
#define CR3 (CT3 + 38)          // 70 staged rows
__global__ __launch_bounds__(256, 2) void conv_kernel(
    const unsigned short* __restrict__ mix,
    const float* __restrict__ conv_w,   // [256][1][39]
    float* __restrict__ out) {
    __shared__ __align__(16) unsigned short lds[CR3 * 256];   // 35 KB

    const int tid = threadIdx.x;
    const int blk = blockIdx.x;
    const int b   = blk / 125;
    const int t0  = (blk % 125) * CT3;

    // ---- stage: 70*256/8 = 2240 u16x8 chunks, 256 threads, 9 iters ----
#pragma unroll
    for (int it = 0; it < 9; ++it) {
        int chunk = it * 256 + tid;
        if (it == 8 && tid >= 192) break;
        int e = chunk * 8;
        int s = e >> 8, c = e & 255;
        int t = t0 - 19 + s;
        u16x8 o;
        if (t >= 0 && t < NT) {
            o = *reinterpret_cast<const u16x8*>(&mix[((size_t)b * NT + t) * OUT_CH + c]);
        } else {
#pragma unroll
            for (int k = 0; k < 8; ++k) o[k] = 0;
        }
        *reinterpret_cast<u16x8*>(&lds[s * 256 + c]) = o;
    }
    __syncthreads();

    const int c = tid;
    float cw[39];
#pragma unroll
    for (int j = 0; j < 39; ++j) cw[j] = conv_w[c * 39 + j];

    float vwin[CR3];
#pragma unroll
    for (int i = 0; i < CR3; ++i)
        vwin[i] = bf2f(lds[i * 256 + c]);

    float* outb = out + ((size_t)b * NT + t0) * OUT_CH + c;
#pragma unroll
    for (int g = 0; g < 4; ++g) {
        float acc[8];
#pragma unroll
        for (int o = 0; o < 8; ++o) {
            float a = vwin[g * 8 + o + 19];      // identity (xp + conv)
#pragma unroll
            for (int j = 0; j < 39; ++j)
                a += cw[j] * vwin[g * 8 + o + j];
            acc[o] = a;
        }
#pragma unroll
        for (int o = 0; o < 8; ++o)
            outb[(size_t)(g * 8 + o) * OUT_CH] = acc[o];
    }
}

// ---------- launch ----------
extern "C" void kernel_launch(void* const* d_in, const int* in_sizes, int n_in,
                              void* d_out, int out_size, void* d_ws, size_t ws_size,
                              hipStream_t stream) {
    const float* x      = (const float*)d_in[0];
    const float* w1     = (const float*)d_in[1];
    const float* b1     = (const float*)d_in[2];
    const float* w2     = (const float*)d_in[3];
    const float* conv_w = (const float*)d_in[4];
    const float* gate_w = (const float*)d_in[5];
    const float* gate_b = (const float*)d_in[6];
    const float* tau    = (const float*)d_in[7];
    float* out = (float*)d_out;

    char* ws = (char*)d_ws;
    unsigned short* w1b = (unsigned short*)(ws);
    unsigned short* w2b = (unsigned short*)(ws + 1048576);
    unsigned short* mix = (unsigned short*)(ws + 2097152);
    float* psum  = (float*)(ws + 2097152 + 2 * 16384000);
    float* psq   = psum + 256 * 256;
    float* probs = psq + 256 * 256;

    cvt_kernel<<<dim3(1024), dim3(256), 0, stream>>>(w1, w1b, w2, w2b);
    reduce_kernel<<<dim3(256), dim3(256), 0, stream>>>(x, psum, psq);
    gate_kernel<<<dim3(1), dim3(256), 0, stream>>>(psum, psq, gate_w, gate_b, tau,
                                                   probs, out + 8192000);
    gemm_kernel<<<dim3(500), dim3(256), 0, stream>>>(x, w1b, w2b, b1, probs, mix);
    conv_kernel<<<dim3(1000), dim3(256), 0, stream>>>(mix, conv_w, out);
}

// Round 17
// 139.337 us; speedup vs baseline: 1.5745x; 1.1429x over previous
//
#include <hip/hip_runtime.h>

// ---------- types ----------
typedef __bf16 bf16x8 __attribute__((ext_vector_type(8)));
typedef float  f32x4  __attribute__((ext_vector_type(4)));
typedef unsigned short u16x8 __attribute__((ext_vector_type(8)));

#define IN_CH  256
#define OUT_CH 256
#define HIDDEN 2048
#define NB     8
#define NT     4000
#define NROW   32000   // NB*NT
#define F1LD   70      // f1t row stride: 35 dwords -> a2 banks (3*l15+4*lg), <=2-way
#define RCHK   50      // reduce chunks per batch (80 rows each)

__device__ __forceinline__ unsigned short bfbits(float f) {
    __bf16 h = (__bf16)f;                       // native cvt (RTNE)
    return *reinterpret_cast<unsigned short*>(&h);
}
__device__ __forceinline__ float bf2f(unsigned short h) {
    return __uint_as_float(((unsigned)h) << 16);
}

#define GLOAD_LDS16(g, l) \
    __builtin_amdgcn_global_load_lds((const __attribute__((address_space(1))) void*)(g), \
                                     (__attribute__((address_space(3))) void*)(l), 16, 0, 0)

// ---------- 1. fp32 -> bf16 convert (both weight tensors, one launch) ----------
__global__ void cvt_kernel(const float* __restrict__ w1,
                           unsigned short* __restrict__ w1o,
                           const float* __restrict__ w2,
                           unsigned short* __restrict__ w2o) {
    int i = blockIdx.x * blockDim.x + threadIdx.x;   // 0..262143
    const float* in;
    unsigned short* outp;
    int j;
    if (i < 131072) { in = w1; outp = w1o; j = i; }
    else            { in = w2; outp = w2o; j = i - 131072; }
    float4 v = reinterpret_cast<const float4*>(in)[j];
    ushort4 o;
    o.x = bfbits(v.x); o.y = bfbits(v.y); o.z = bfbits(v.z); o.w = bfbits(v.w);
    reinterpret_cast<ushort4*>(outp)[j] = o;
}

// ---------- 2. partial mean/var reduction, float4 lanes ----------
// R16's reduce: 256 blocks, scalar 4B loads, 125 serial iters -> ~23us
// latency-bound (1 wave/SIMD, 256B/instr). Now: 400 blocks (8 b x 50 chunks
// of 80 rows), lane = float4 (16B -> 1KB/wave-instr), 4 row-groups, 20
// fully-unrolled iterations, LDS combine. Predicted ~6-8us.
__global__ __launch_bounds__(256) void reduce_kernel(const float* __restrict__ x,
                              float* __restrict__ psum, float* __restrict__ psq) {
    __shared__ float sbuf[4][260];
    __shared__ float qbuf[4][260];
    const int tid  = threadIdx.x;
    const int quad = tid & 63;        // float4 column (64 x 4 = 256 ch)
    const int trow = tid >> 6;        // 0..3 row group
    const int blk  = blockIdx.x;
    const int b    = blk / RCHK, tc = blk % RCHK;
    const float* base = x + ((size_t)b * NT + tc * 80 + trow) * IN_CH + quad * 4;
    float s0=0.f,s1=0.f,s2=0.f,s3=0.f,q0=0.f,q1=0.f,q2=0.f,q3=0.f;
#pragma unroll
    for (int it = 0; it < 20; ++it) {
        float4 v = *reinterpret_cast<const float4*>(base + (size_t)it * 4 * IN_CH);
        s0 += v.x; s1 += v.y; s2 += v.z; s3 += v.w;
        q0 += v.x * v.x; q1 += v.y * v.y; q2 += v.z * v.z; q3 += v.w * v.w;
    }
    sbuf[trow][quad * 4 + 0] = s0; sbuf[trow][quad * 4 + 1] = s1;
    sbuf[trow][quad * 4 + 2] = s2; sbuf[trow][quad * 4 + 3] = s3;
    qbuf[trow][quad * 4 + 0] = q0; qbuf[trow][quad * 4 + 1] = q1;
    qbuf[trow][quad * 4 + 2] = q2; qbuf[trow][quad * 4 + 3] = q3;
    __syncthreads();
    float ss = sbuf[0][tid] + sbuf[1][tid] + sbuf[2][tid] + sbuf[3][tid];
    float qq = qbuf[0][tid] + qbuf[1][tid] + qbuf[2][tid] + qbuf[3][tid];
    psum[blk * IN_CH + tid] = ss;
    psq [blk * IN_CH + tid] = qq;
}

// ---------- 3. gate: mean/std -> logits -> probs -> losses ----------
__global__ __launch_bounds__(256) void gate_kernel(
    const float* __restrict__ psum, const float* __restrict__ psq,
    const float* __restrict__ gate_w, const float* __restrict__ gate_b,
    const float* __restrict__ tau, float* __restrict__ probs,
    float* __restrict__ losses) {
    __shared__ float gi[NB][2 * IN_CH];
    __shared__ float part[16][17];
    __shared__ float lgt[16];
    int tid = threadIdx.x;
    for (int b = 0; b < NB; ++b) {
        float s = 0.f, q = 0.f;
        for (int p = 0; p < RCHK; ++p) {
            s += psum[(b * RCHK + p) * IN_CH + tid];
            q += psq [(b * RCHK + p) * IN_CH + tid];
        }
        float mean = s * (1.f / 4000.f);
        float var  = (q - s * s * (1.f / 4000.f)) * (1.f / 3999.f);  // ddof=1
        gi[b][tid]          = mean;
        gi[b][IN_CH + tid]  = sqrtf(fmaxf(var, 0.f));
    }
    __syncthreads();
    {
        int pair = tid >> 4, seg = tid & 15;     // pair = b*2+k
        int b = pair >> 1, k = pair & 1;
        float d = 0.f;
        for (int i = seg * 32; i < seg * 32 + 32; ++i)
            d += gi[b][i] * gate_w[k * 2 * IN_CH + i];
        part[pair][seg] = d;
    }
    __syncthreads();
    if (tid < 16) {
        float d = 0.f;
        for (int s = 0; s < 16; ++s) d += part[tid][s];
        lgt[tid] = tau[0] * (d + gate_b[tid & 1]);
    }
    __syncthreads();
    if (tid == 0) {
        float pr[16];
        float i0 = 0.f, i1 = 0.f, sp = 0.f;
        for (int b = 0; b < NB; ++b) {
            float a = lgt[b * 2], c2 = lgt[b * 2 + 1];
            float mx = fmaxf(a, c2);
            float e0 = expf(a - mx), e1 = expf(c2 - mx);
            float inv = 1.f / (e0 + e1);
            float q0 = e0 * inv, q1 = e1 * inv;
            pr[b * 2] = q0; pr[b * 2 + 1] = q1;
            i0 += q0; i1 += q1;
            float nrm = sqrtf(q0 * q0 + q1 * q1) + 1e-8f;
            sp += (q0 + q1) / nrm;
        }
        losses[0] = 0.1f * sp * (1.f / 8.f);
        i0 *= (1.f / 8.f); i1 *= (1.f / 8.f);
        float meanI = 0.5f * (i0 + i1);
        float stdI  = fabsf(i0 - i1) * 0.7071067811865476f;
        float cv = stdI / (meanI + 1e-8f);
        losses[1] = 0.01f * cv * cv;
        for (int t = 0; t < 16; ++t) probs[t] = pr[t];
    }
}

// ---------- 4. fused GEMM1(relu)+GEMM2 -> mixed output (frozen: R12/R15) ----
__global__ __launch_bounds__(256, 2) void gemm_kernel(
    const float* __restrict__ x,
    const unsigned short* __restrict__ w1b,   // [2048][256] bf16
    const unsigned short* __restrict__ w2b,   // [256][2048] bf16
    const float* __restrict__ b1,
    const float* __restrict__ probs,          // [8][2]
    unsigned short* __restrict__ mix) {       // [32000][256] bf16 (pre-mixed)
    __shared__ __align__(16) unsigned short w1c[64 * 256];   // 32 KB
    __shared__ __align__(16) unsigned short w2c[256 * 64];   // 32 KB
    __shared__ __align__(16) unsigned short f1t[64 * F1LD];  // 8.75 KB

    const int tid   = threadIdx.x;
    const int lane  = tid & 63;
    const int wv    = tid >> 6;       // 0..3
    const int rb    = wv & 1;         // 32-row band
    const int ch    = wv >> 1;        // 0..1 oc half (128 each)
    const int m0    = blockIdx.x * 64;
    const int l15   = lane & 15;
    const int lg    = lane >> 4;      // 0..3

    bf16x8 xr[2][8];
#pragma unroll
    for (int rt = 0; rt < 2; ++rt) {
        const float* xrow = x + (size_t)(m0 + rb * 32 + rt * 16 + l15) * IN_CH;
#pragma unroll
        for (int kk = 0; kk < 8; ++kk) {
            float4 v0 = *reinterpret_cast<const float4*>(xrow + kk * 32 + lg * 8);
            float4 v1 = *reinterpret_cast<const float4*>(xrow + kk * 32 + lg * 8 + 4);
            bf16x8 h;
            h[0] = (__bf16)v0.x; h[1] = (__bf16)v0.y; h[2] = (__bf16)v0.z; h[3] = (__bf16)v0.w;
            h[4] = (__bf16)v1.x; h[5] = (__bf16)v1.y; h[6] = (__bf16)v1.z; h[7] = (__bf16)v1.w;
            xr[rt][kk] = h;
        }
    }

    f32x4 acc2[2][8];
#pragma unroll
    for (int rt = 0; rt < 2; ++rt)
#pragma unroll
        for (int t = 0; t < 8; ++t) { acc2[rt][t][0]=0.f; acc2[rt][t][1]=0.f; acc2[rt][t][2]=0.f; acc2[rt][t][3]=0.f; }

#pragma unroll 1
    for (int chunk = 0; chunk < 32; ++chunk) {
        {
            const int h0 = chunk * 64;
            const unsigned short* w1s = w1b + (size_t)h0 * IN_CH;
            const unsigned short* w2s = w2b + h0;
#pragma unroll
            for (int i = 0; i < 8; ++i) {
                int seg = i * 4 + wv;                       // 0..31
                int r1 = seg * 2 + (lane >> 5);
                int c1 = ((lane & 31) * 8) ^ ((r1 & 7) << 3);
                GLOAD_LDS16(w1s + r1 * 256 + c1, &w1c[seg * 512]);
                int r2 = seg * 8 + (lane >> 3);
                int c2 = ((lane & 7) * 8) ^ ((r2 & 7) << 3);
                GLOAD_LDS16(w2s + (size_t)r2 * HIDDEN + c2, &w2c[seg * 512]);
            }
        }

        __syncthreads();   // [A] vmcnt drained -> weights ready

        f32x4 acc1[2][2];
#pragma unroll
        for (int rt = 0; rt < 2; ++rt)
#pragma unroll
            for (int ht = 0; ht < 2; ++ht) { acc1[rt][ht][0]=0.f; acc1[rt][ht][1]=0.f; acc1[rt][ht][2]=0.f; acc1[rt][ht][3]=0.f; }
#pragma unroll
        for (int kk = 0; kk < 8; ++kk) {
            const int kE = kk * 32 + lg * 8;
            bf16x8 bb[2];
#pragma unroll
            for (int ht = 0; ht < 2; ++ht) {
                const int hl = ch * 32 + ht * 16 + l15;
                bb[ht] = *reinterpret_cast<const bf16x8*>(
                    &w1c[hl * 256 + (kE ^ ((hl & 7) << 3))]);
            }
#pragma unroll
            for (int rt = 0; rt < 2; ++rt)
#pragma unroll
                for (int ht = 0; ht < 2; ++ht)
                    acc1[rt][ht] = __builtin_amdgcn_mfma_f32_16x16x32_bf16(
                        xr[rt][kk], bb[ht], acc1[rt][ht], 0, 0, 0);
        }
#pragma unroll
        for (int ht = 0; ht < 2; ++ht) {
            const int hl = ch * 32 + ht * 16 + l15;
            const float bias = b1[chunk * 64 + hl];   // L2-hit scalar
#pragma unroll
            for (int rt = 0; rt < 2; ++rt)
#pragma unroll
                for (int r = 0; r < 4; ++r) {
                    float v = fmaxf(acc1[rt][ht][r] + bias, 0.f);
                    int rr = rb * 32 + rt * 16 + lg * 4 + r;
                    f1t[rr * F1LD + hl] = bfbits(v);
                }
        }

        __syncthreads();   // [B] f1t ready

#pragma unroll
        for (int kk = 0; kk < 2; ++kk) {
            const int kE = kk * 32 + lg * 8;
            bf16x8 a2[2];
#pragma unroll
            for (int rt = 0; rt < 2; ++rt)
                a2[rt] = *reinterpret_cast<const bf16x8*>(
                    &f1t[(rb * 32 + rt * 16 + l15) * F1LD + kE]);
#pragma unroll
            for (int t = 0; t < 8; ++t) {
                int oc = ch * 128 + t * 16 + l15;
                bf16x8 b2 = *reinterpret_cast<const bf16x8*>(
                    &w2c[oc * 64 + (kE ^ ((oc & 7) << 3))]);
#pragma unroll
                for (int rt = 0; rt < 2; ++rt)
                    acc2[rt][t] = __builtin_amdgcn_mfma_f32_16x16x32_bf16(
                        a2[rt], b2, acc2[rt][t], 0, 0, 0);
            }
        }

        if (chunk == 3) {   // small branch done: rescale so p0*acc2 = p0*full+p1*small
#pragma unroll
            for (int rt = 0; rt < 2; ++rt)
#pragma unroll
                for (int r = 0; r < 4; ++r) {
                    int rr = m0 + rb * 32 + rt * 16 + lg * 4 + r;
                    int bb = rr / 4000;
                    float p0 = probs[bb * 2], p1 = probs[bb * 2 + 1];
                    float ratio = (p0 + p1) / fmaxf(p0, 1e-30f);
#pragma unroll
                    for (int t = 0; t < 8; ++t)
                        acc2[rt][t][r] *= ratio;
                }
        }

        __syncthreads();   // [C] reads done -> next stage may overwrite
    }
    // final: mix = p0 * acc2 (= p0*full + p1*small)
#pragma unroll
    for (int rt = 0; rt < 2; ++rt)
#pragma unroll
        for (int r = 0; r < 4; ++r) {
            int rr = m0 + rb * 32 + rt * 16 + lg * 4 + r;
            int bb = rr / 4000;
            float p0 = probs[bb * 2];
#pragma unroll
            for (int t = 0; t < 8; ++t) {
                int oc = ch * 128 + t * 16 + l15;
                mix[(size_t)rr * OUT_CH + oc] = bfbits(p0 * acc2[rt][t][r]);
            }
        }
}

// ---------- 5. depthwise conv: window-in-registers (frozen: R16) ----------
#define CT3 32                  // t outputs per block
#define CR3 (CT3 + 38)          // 70 staged rows
__global__ __launch_bounds__(256, 2) void conv_kernel(
    const unsigned short* __restrict__ mix,
    const float* __restrict__ conv_w,   // [256][1][39]
    float* __restrict__ out) {
    __shared__ __align__(16) unsigned short lds[CR3 * 256];   // 35 KB

    const int tid = threadIdx.x;
    const int blk = blockIdx.x;
    const int b   = blk / 125;
    const int t0  = (blk % 125) * CT3;

#pragma unroll
    for (int it = 0; it < 9; ++it) {
        int chunk = it * 256 + tid;
        if (it == 8 && tid >= 192) break;
        int e = chunk * 8;
        int s = e >> 8, c = e & 255;
        int t = t0 - 19 + s;
        u16x8 o;
        if (t >= 0 && t < NT) {
            o = *reinterpret_cast<const u16x8*>(&mix[((size_t)b * NT + t) * OUT_CH + c]);
        } else {
#pragma unroll
            for (int k = 0; k < 8; ++k) o[k] = 0;
        }
        *reinterpret_cast<u16x8*>(&lds[s * 256 + c]) = o;
    }
    __syncthreads();

    const int c = tid;
    float cw[39];
#pragma unroll
    for (int j = 0; j < 39; ++j) cw[j] = conv_w[c * 39 + j];

    float vwin[CR3];
#pragma unroll
    for (int i = 0; i < CR3; ++i)
        vwin[i] = bf2f(lds[i * 256 + c]);

    float* outb = out + ((size_t)b * NT + t0) * OUT_CH + c;
#pragma unroll
    for (int g = 0; g < 4; ++g) {
        float acc[8];
#pragma unroll
        for (int o = 0; o < 8; ++o) {
            float a = vwin[g * 8 + o + 19];      // identity (xp + conv)
#pragma unroll
            for (int j = 0; j < 39; ++j)
                a += cw[j] * vwin[g * 8 + o + j];
            acc[o] = a;
        }
#pragma unroll
        for (int o = 0; o < 8; ++o)
            outb[(size_t)(g * 8 + o) * OUT_CH] = acc[o];
    }
}

// ---------- launch ----------
extern "C" void kernel_launch(void* const* d_in, const int* in_sizes, int n_in,
                              void* d_out, int out_size, void* d_ws, size_t ws_size,
                              hipStream_t stream) {
    const float* x      = (const float*)d_in[0];
    const float* w1     = (const float*)d_in[1];
    const float* b1     = (const float*)d_in[2];
    const float* w2     = (const float*)d_in[3];
    const float* conv_w = (const float*)d_in[4];
    const float* gate_w = (const float*)d_in[5];
    const float* gate_b = (const float*)d_in[6];
    const float* tau    = (const float*)d_in[7];
    float* out = (float*)d_out;

    char* ws = (char*)d_ws;
    unsigned short* w1b = (unsigned short*)(ws);
    unsigned short* w2b = (unsigned short*)(ws + 1048576);
    unsigned short* mix = (unsigned short*)(ws + 2097152);
    float* psum  = (float*)(ws + 2097152 + 16384000);
    float* psq   = psum + NB * RCHK * IN_CH;
    float* probs = psq + NB * RCHK * IN_CH;

    cvt_kernel<<<dim3(1024), dim3(256), 0, stream>>>(w1, w1b, w2, w2b);
    reduce_kernel<<<dim3(NB * RCHK), dim3(256), 0, stream>>>(x, psum, psq);
    gate_kernel<<<dim3(1), dim3(256), 0, stream>>>(psum, psq, gate_w, gate_b, tau,
                                                   probs, out + 8192000);
    gemm_kernel<<<dim3(500), dim3(256), 0, stream>>>(x, w1b, w2b, b1, probs, mix);
    conv_kernel<<<dim3(1000), dim3(256), 0, stream>>>(mix, conv_w, out);
}

// Round 18
// 135.122 us; speedup vs baseline: 1.6236x; 1.0312x over previous
//
#include <hip/hip_runtime.h>

// ---------- types ----------
typedef __bf16 bf16x8 __attribute__((ext_vector_type(8)));
typedef float  f32x4  __attribute__((ext_vector_type(4)));
typedef unsigned short u16x8 __attribute__((ext_vector_type(8)));

#define IN_CH  256
#define OUT_CH 256
#define HIDDEN 2048
#define NB     8
#define NT     4000
#define NROW   32000   // NB*NT
#define F1LD   70      // f1t row stride: 35 dwords -> a2 banks (3*l15+4*lg), <=2-way
#define RCHK   50      // reduce chunks per batch (80 rows each)

__device__ __forceinline__ unsigned short bfbits(float f) {
    __bf16 h = (__bf16)f;                       // native cvt (RTNE)
    return *reinterpret_cast<unsigned short*>(&h);
}
__device__ __forceinline__ float bf2f(unsigned short h) {
    return __uint_as_float(((unsigned)h) << 16);
}

#define GLOAD_LDS16(g, l) \
    __builtin_amdgcn_global_load_lds((const __attribute__((address_space(1))) void*)(g), \
                                     (__attribute__((address_space(3))) void*)(l), 16, 0, 0)

// ---------- 1. prep: cvt (blocks 0..1023) + reduce (blocks 1024..1423) ----------
// Pure grid union -- no atomics, no cross-block deps (R14's gate-in-kernel
// variant cost +21us; this only merges the two INDEPENDENT streaming kernels
// so cvt's ~2us hides under reduce's ~6us and one launch gap is saved).
__global__ __launch_bounds__(256) void prep_kernel(
    const float* __restrict__ w1, unsigned short* __restrict__ w1o,
    const float* __restrict__ w2, unsigned short* __restrict__ w2o,
    const float* __restrict__ x,
    float* __restrict__ psum, float* __restrict__ psq) {
    const int tid = threadIdx.x;
    const int blk = blockIdx.x;

    if (blk < 1024) {   // ---- cvt: 262144 float4 chunks over w1,w2 ----
        int i = blk * 256 + tid;
        const float* in; unsigned short* outp; int j;
        if (i < 131072) { in = w1; outp = w1o; j = i; }
        else            { in = w2; outp = w2o; j = i - 131072; }
        float4 v = reinterpret_cast<const float4*>(in)[j];
        ushort4 o;
        o.x = bfbits(v.x); o.y = bfbits(v.y); o.z = bfbits(v.z); o.w = bfbits(v.w);
        reinterpret_cast<ushort4*>(outp)[j] = o;
        return;
    }

    // ---- reduce: float4 lanes, 80-row chunk, 20 unrolled iters ----
    __shared__ float sbuf[4][260];
    __shared__ float qbuf[4][260];
    const int quad = tid & 63;        // float4 column (64 x 4 = 256 ch)
    const int trow = tid >> 6;        // 0..3 row group
    const int rblk = blk - 1024;      // 0..399
    const int b    = rblk / RCHK, tc = rblk % RCHK;
    const float* base = x + ((size_t)b * NT + tc * 80 + trow) * IN_CH + quad * 4;
    float s0=0.f,s1=0.f,s2=0.f,s3=0.f,q0=0.f,q1=0.f,q2=0.f,q3=0.f;
#pragma unroll
    for (int it = 0; it < 20; ++it) {
        float4 v = *reinterpret_cast<const float4*>(base + (size_t)it * 4 * IN_CH);
        s0 += v.x; s1 += v.y; s2 += v.z; s3 += v.w;
        q0 += v.x * v.x; q1 += v.y * v.y; q2 += v.z * v.z; q3 += v.w * v.w;
    }
    sbuf[trow][quad * 4 + 0] = s0; sbuf[trow][quad * 4 + 1] = s1;
    sbuf[trow][quad * 4 + 2] = s2; sbuf[trow][quad * 4 + 3] = s3;
    qbuf[trow][quad * 4 + 0] = q0; qbuf[trow][quad * 4 + 1] = q1;
    qbuf[trow][quad * 4 + 2] = q2; qbuf[trow][quad * 4 + 3] = q3;
    __syncthreads();
    float ss = sbuf[0][tid] + sbuf[1][tid] + sbuf[2][tid] + sbuf[3][tid];
    float qq = qbuf[0][tid] + qbuf[1][tid] + qbuf[2][tid] + qbuf[3][tid];
    psum[rblk * IN_CH + tid] = ss;
    psq [rblk * IN_CH + tid] = qq;
}

// ---------- 2. gate: mean/std -> logits -> probs -> losses ----------
__global__ __launch_bounds__(256) void gate_kernel(
    const float* __restrict__ psum, const float* __restrict__ psq,
    const float* __restrict__ gate_w, const float* __restrict__ gate_b,
    const float* __restrict__ tau, float* __restrict__ probs,
    float* __restrict__ losses) {
    __shared__ float gi[NB][2 * IN_CH];
    __shared__ float part[16][17];
    __shared__ float lgt[16];
    int tid = threadIdx.x;
    for (int b = 0; b < NB; ++b) {
        float s = 0.f, q = 0.f;
        for (int p = 0; p < RCHK; ++p) {
            s += psum[(b * RCHK + p) * IN_CH + tid];
            q += psq [(b * RCHK + p) * IN_CH + tid];
        }
        float mean = s * (1.f / 4000.f);
        float var  = (q - s * s * (1.f / 4000.f)) * (1.f / 3999.f);  // ddof=1
        gi[b][tid]          = mean;
        gi[b][IN_CH + tid]  = sqrtf(fmaxf(var, 0.f));
    }
    __syncthreads();
    {
        int pair = tid >> 4, seg = tid & 15;     // pair = b*2+k
        int b = pair >> 1, k = pair & 1;
        float d = 0.f;
        for (int i = seg * 32; i < seg * 32 + 32; ++i)
            d += gi[b][i] * gate_w[k * 2 * IN_CH + i];
        part[pair][seg] = d;
    }
    __syncthreads();
    if (tid < 16) {
        float d = 0.f;
        for (int s = 0; s < 16; ++s) d += part[tid][s];
        lgt[tid] = tau[0] * (d + gate_b[tid & 1]);
    }
    __syncthreads();
    if (tid == 0) {
        float pr[16];
        float i0 = 0.f, i1 = 0.f, sp = 0.f;
        for (int b = 0; b < NB; ++b) {
            float a = lgt[b * 2], c2 = lgt[b * 2 + 1];
            float mx = fmaxf(a, c2);
            float e0 = expf(a - mx), e1 = expf(c2 - mx);
            float inv = 1.f / (e0 + e1);
            float q0 = e0 * inv, q1 = e1 * inv;
            pr[b * 2] = q0; pr[b * 2 + 1] = q1;
            i0 += q0; i1 += q1;
            float nrm = sqrtf(q0 * q0 + q1 * q1) + 1e-8f;
            sp += (q0 + q1) / nrm;
        }
        losses[0] = 0.1f * sp * (1.f / 8.f);
        i0 *= (1.f / 8.f); i1 *= (1.f / 8.f);
        float meanI = 0.5f * (i0 + i1);
        float stdI  = fabsf(i0 - i1) * 0.7071067811865476f;
        float cv = stdI / (meanI + 1e-8f);
        losses[1] = 0.01f * cv * cv;
        for (int t = 0; t < 16; ++t) probs[t] = pr[t];
    }
}

// ---------- 3. fused GEMM1(relu)+GEMM2 -> mixed output (frozen: R12/R15) ----
__global__ __launch_bounds__(256, 2) void gemm_kernel(
    const float* __restrict__ x,
    const unsigned short* __restrict__ w1b,   // [2048][256] bf16
    const unsigned short* __restrict__ w2b,   // [256][2048] bf16
    const float* __restrict__ b1,
    const float* __restrict__ probs,          // [8][2]
    unsigned short* __restrict__ mix) {       // [32000][256] bf16 (pre-mixed)
    __shared__ __align__(16) unsigned short w1c[64 * 256];   // 32 KB
    __shared__ __align__(16) unsigned short w2c[256 * 64];   // 32 KB
    __shared__ __align__(16) unsigned short f1t[64 * F1LD];  // 8.75 KB

    const int tid   = threadIdx.x;
    const int lane  = tid & 63;
    const int wv    = tid >> 6;       // 0..3
    const int rb    = wv & 1;         // 32-row band
    const int ch    = wv >> 1;        // 0..1 oc half (128 each)
    const int m0    = blockIdx.x * 64;
    const int l15   = lane & 15;
    const int lg    = lane >> 4;      // 0..3

    bf16x8 xr[2][8];
#pragma unroll
    for (int rt = 0; rt < 2; ++rt) {
        const float* xrow = x + (size_t)(m0 + rb * 32 + rt * 16 + l15) * IN_CH;
#pragma unroll
        for (int kk = 0; kk < 8; ++kk) {
            float4 v0 = *reinterpret_cast<const float4*>(xrow + kk * 32 + lg * 8);
            float4 v1 = *reinterpret_cast<const float4*>(xrow + kk * 32 + lg * 8 + 4);
            bf16x8 h;
            h[0] = (__bf16)v0.x; h[1] = (__bf16)v0.y; h[2] = (__bf16)v0.z; h[3] = (__bf16)v0.w;
            h[4] = (__bf16)v1.x; h[5] = (__bf16)v1.y; h[6] = (__bf16)v1.z; h[7] = (__bf16)v1.w;
            xr[rt][kk] = h;
        }
    }

    f32x4 acc2[2][8];
#pragma unroll
    for (int rt = 0; rt < 2; ++rt)
#pragma unroll
        for (int t = 0; t < 8; ++t) { acc2[rt][t][0]=0.f; acc2[rt][t][1]=0.f; acc2[rt][t][2]=0.f; acc2[rt][t][3]=0.f; }

#pragma unroll 1
    for (int chunk = 0; chunk < 32; ++chunk) {
        {
            const int h0 = chunk * 64;
            const unsigned short* w1s = w1b + (size_t)h0 * IN_CH;
            const unsigned short* w2s = w2b + h0;
#pragma unroll
            for (int i = 0; i < 8; ++i) {
                int seg = i * 4 + wv;                       // 0..31
                int r1 = seg * 2 + (lane >> 5);
                int c1 = ((lane & 31) * 8) ^ ((r1 & 7) << 3);
                GLOAD_LDS16(w1s + r1 * 256 + c1, &w1c[seg * 512]);
                int r2 = seg * 8 + (lane >> 3);
                int c2 = ((lane & 7) * 8) ^ ((r2 & 7) << 3);
                GLOAD_LDS16(w2s + (size_t)r2 * HIDDEN + c2, &w2c[seg * 512]);
            }
        }

        __syncthreads();   // [A] vmcnt drained -> weights ready

        f32x4 acc1[2][2];
#pragma unroll
        for (int rt = 0; rt < 2; ++rt)
#pragma unroll
            for (int ht = 0; ht < 2; ++ht) { acc1[rt][ht][0]=0.f; acc1[rt][ht][1]=0.f; acc1[rt][ht][2]=0.f; acc1[rt][ht][3]=0.f; }
#pragma unroll
        for (int kk = 0; kk < 8; ++kk) {
            const int kE = kk * 32 + lg * 8;
            bf16x8 bb[2];
#pragma unroll
            for (int ht = 0; ht < 2; ++ht) {
                const int hl = ch * 32 + ht * 16 + l15;
                bb[ht] = *reinterpret_cast<const bf16x8*>(
                    &w1c[hl * 256 + (kE ^ ((hl & 7) << 3))]);
            }
#pragma unroll
            for (int rt = 0; rt < 2; ++rt)
#pragma unroll
                for (int ht = 0; ht < 2; ++ht)
                    acc1[rt][ht] = __builtin_amdgcn_mfma_f32_16x16x32_bf16(
                        xr[rt][kk], bb[ht], acc1[rt][ht], 0, 0, 0);
        }
#pragma unroll
        for (int ht = 0; ht < 2; ++ht) {
            const int hl = ch * 32 + ht * 16 + l15;
            const float bias = b1[chunk * 64 + hl];   // L2-hit scalar
#pragma unroll
            for (int rt = 0; rt < 2; ++rt)
#pragma unroll
                for (int r = 0; r < 4; ++r) {
                    float v = fmaxf(acc1[rt][ht][r] + bias, 0.f);
                    int rr = rb * 32 + rt * 16 + lg * 4 + r;
                    f1t[rr * F1LD + hl] = bfbits(v);
                }
        }

        __syncthreads();   // [B] f1t ready

#pragma unroll
        for (int kk = 0; kk < 2; ++kk) {
            const int kE = kk * 32 + lg * 8;
            bf16x8 a2[2];
#pragma unroll
            for (int rt = 0; rt < 2; ++rt)
                a2[rt] = *reinterpret_cast<const bf16x8*>(
                    &f1t[(rb * 32 + rt * 16 + l15) * F1LD + kE]);
#pragma unroll
            for (int t = 0; t < 8; ++t) {
                int oc = ch * 128 + t * 16 + l15;
                bf16x8 b2 = *reinterpret_cast<const bf16x8*>(
                    &w2c[oc * 64 + (kE ^ ((oc & 7) << 3))]);
#pragma unroll
                for (int rt = 0; rt < 2; ++rt)
                    acc2[rt][t] = __builtin_amdgcn_mfma_f32_16x16x32_bf16(
                        a2[rt], b2, acc2[rt][t], 0, 0, 0);
            }
        }

        if (chunk == 3) {   // small branch done: rescale so p0*acc2 = p0*full+p1*small
#pragma unroll
            for (int rt = 0; rt < 2; ++rt)
#pragma unroll
                for (int r = 0; r < 4; ++r) {
                    int rr = m0 + rb * 32 + rt * 16 + lg * 4 + r;
                    int bb = rr / 4000;
                    float p0 = probs[bb * 2], p1 = probs[bb * 2 + 1];
                    float ratio = (p0 + p1) / fmaxf(p0, 1e-30f);
#pragma unroll
                    for (int t = 0; t < 8; ++t)
                        acc2[rt][t][r] *= ratio;
                }
        }

        __syncthreads();   // [C] reads done -> next stage may overwrite
    }
    // final: mix = p0 * acc2 (= p0*full + p1*small)
#pragma unroll
    for (int rt = 0; rt < 2; ++rt)
#pragma unroll
        for (int r = 0; r < 4; ++r) {
            int rr = m0 + rb * 32 + rt * 16 + lg * 4 + r;
            int bb = rr / 4000;
            float p0 = probs[bb * 2];
#pragma unroll
            for (int t = 0; t < 8; ++t) {
                int oc = ch * 128 + t * 16 + l15;
                mix[(size_t)rr * OUT_CH + oc] = bfbits(p0 * acc2[rt][t][r]);
            }
        }
}

// ---------- 4. depthwise conv: window-in-registers (frozen: R16) ----------
#define CT3 32                  // t outputs per block
#define CR3 (CT3 + 38)          // 70 staged rows
__global__ __launch_bounds__(256, 2) void conv_kernel(
    const unsigned short* __restrict__ mix,
    const float* __restrict__ conv_w,   // [256][1][39]
    float* __restrict__ out) {
    __shared__ __align__(16) unsigned short lds[CR3 * 256];   // 35 KB

    const int tid = threadIdx.x;
    const int blk = blockIdx.x;
    const int b   = blk / 125;
    const int t0  = (blk % 125) * CT3;

#pragma unroll
    for (int it = 0; it < 9; ++it) {
        int chunk = it * 256 + tid;
        if (it == 8 && tid >= 192) break;
        int e = chunk * 8;
        int s = e >> 8, c = e & 255;
        int t = t0 - 19 + s;
        u16x8 o;
        if (t >= 0 && t < NT) {
            o = *reinterpret_cast<const u16x8*>(&mix[((size_t)b * NT + t) * OUT_CH + c]);
        } else {
#pragma unroll
            for (int k = 0; k < 8; ++k) o[k] = 0;
        }
        *reinterpret_cast<u16x8*>(&lds[s * 256 + c]) = o;
    }
    __syncthreads();

    const int c = tid;
    float cw[39];
#pragma unroll
    for (int j = 0; j < 39; ++j) cw[j] = conv_w[c * 39 + j];

    float vwin[CR3];
#pragma unroll
    for (int i = 0; i < CR3; ++i)
        vwin[i] = bf2f(lds[i * 256 + c]);

    float* outb = out + ((size_t)b * NT + t0) * OUT_CH + c;
#pragma unroll
    for (int g = 0; g < 4; ++g) {
        float acc[8];
#pragma unroll
        for (int o = 0; o < 8; ++o) {
            float a = vwin[g * 8 + o + 19];      // identity (xp + conv)
#pragma unroll
            for (int j = 0; j < 39; ++j)
                a += cw[j] * vwin[g * 8 + o + j];
            acc[o] = a;
        }
#pragma unroll
        for (int o = 0; o < 8; ++o)
            outb[(size_t)(g * 8 + o) * OUT_CH] = acc[o];
    }
}

// ---------- launch ----------
extern "C" void kernel_launch(void* const* d_in, const int* in_sizes, int n_in,
                              void* d_out, int out_size, void* d_ws, size_t ws_size,
                              hipStream_t stream) {
    const float* x      = (const float*)d_in[0];
    const float* w1     = (const float*)d_in[1];
    const float* b1     = (const float*)d_in[2];
    const float* w2     = (const float*)d_in[3];
    const float* conv_w = (const float*)d_in[4];
    const float* gate_w = (const float*)d_in[5];
    const float* gate_b = (const float*)d_in[6];
    const float* tau    = (const float*)d_in[7];
    float* out = (float*)d_out;

    char* ws = (char*)d_ws;
    unsigned short* w1b = (unsigned short*)(ws);
    unsigned short* w2b = (unsigned short*)(ws + 1048576);
    unsigned short* mix = (unsigned short*)(ws + 2097152);
    float* psum  = (float*)(ws + 2097152 + 16384000);
    float* psq   = psum + NB * RCHK * IN_CH;
    float* probs = psq + NB * RCHK * IN_CH;

    prep_kernel<<<dim3(1024 + NB * RCHK), dim3(256), 0, stream>>>(
        w1, w1b, w2, w2b, x, psum, psq);
    gate_kernel<<<dim3(1), dim3(256), 0, stream>>>(psum, psq, gate_w, gate_b, tau,
                                                   probs, out + 8192000);
    gemm_kernel<<<dim3(500), dim3(256), 0, stream>>>(x, w1b, w2b, b1, probs, mix);
    conv_kernel<<<dim3(1000), dim3(256), 0, stream>>>(mix, conv_w, out);
}

// Round 19
// 118.642 us; speedup vs baseline: 1.8491x; 1.1389x over previous
//
#include <hip/hip_runtime.h>

// ---------- types ----------
typedef __bf16 bf16x8 __attribute__((ext_vector_type(8)));
typedef float  f32x4  __attribute__((ext_vector_type(4)));
typedef unsigned short u16x8 __attribute__((ext_vector_type(8)));

#define IN_CH  256
#define OUT_CH 256
#define HIDDEN 2048
#define NB     8
#define NT     4000
#define NROW   32000   // NB*NT
#define F1LD   70      // f1t row stride: 35 dwords -> a2 banks (3*l15+4*lg), <=2-way
#define RCHK   50      // reduce chunks per batch (80 rows each)

__device__ __forceinline__ unsigned short bfbits(float f) {
    __bf16 h = (__bf16)f;                       // native cvt (RTNE)
    return *reinterpret_cast<unsigned short*>(&h);
}
__device__ __forceinline__ float bf2f(unsigned short h) {
    return __uint_as_float(((unsigned)h) << 16);
}
// per-thread 2-way softmax from global logits (transient regs only)
__device__ __forceinline__ void spair(const float* __restrict__ lg, int bb,
                                      float& p0, float& p1) {
    float a = lg[bb * 2], c = lg[bb * 2 + 1];
    float mx = fmaxf(a, c);
    float e0 = expf(a - mx), e1 = expf(c - mx);
    float inv = 1.f / (e0 + e1);
    p0 = e0 * inv; p1 = e1 * inv;
}

#define GLOAD_LDS16(g, l) \
    __builtin_amdgcn_global_load_lds((const __attribute__((address_space(1))) void*)(g), \
                                     (__attribute__((address_space(3))) void*)(l), 16, 0, 0)

// ---------- 1. prep: reduce (blocks 0..399) + cvt (blocks 400..1423) ----------
// Reduce first: it's the long pole (~6us); cvt fills remaining CUs.
__global__ __launch_bounds__(256) void prep_kernel(
    const float* __restrict__ w1, unsigned short* __restrict__ w1o,
    const float* __restrict__ w2, unsigned short* __restrict__ w2o,
    const float* __restrict__ x,
    float* __restrict__ psum, float* __restrict__ psq) {
    const int tid = threadIdx.x;
    const int blk = blockIdx.x;

    if (blk >= NB * RCHK) {   // ---- cvt: 262144 float4 chunks over w1,w2 ----
        int i = (blk - NB * RCHK) * 256 + tid;
        const float* in; unsigned short* outp; int j;
        if (i < 131072) { in = w1; outp = w1o; j = i; }
        else            { in = w2; outp = w2o; j = i - 131072; }
        float4 v = reinterpret_cast<const float4*>(in)[j];
        ushort4 o;
        o.x = bfbits(v.x); o.y = bfbits(v.y); o.z = bfbits(v.z); o.w = bfbits(v.w);
        reinterpret_cast<ushort4*>(outp)[j] = o;
        return;
    }

    // ---- reduce: float4 lanes, 80-row chunk, 20 unrolled iters ----
    __shared__ float sbuf[4][260];
    __shared__ float qbuf[4][260];
    const int quad = tid & 63;        // float4 column (64 x 4 = 256 ch)
    const int trow = tid >> 6;        // 0..3 row group
    const int b    = blk / RCHK, tc = blk % RCHK;
    const float* base = x + ((size_t)b * NT + tc * 80 + trow) * IN_CH + quad * 4;
    float s0=0.f,s1=0.f,s2=0.f,s3=0.f,q0=0.f,q1=0.f,q2=0.f,q3=0.f;
#pragma unroll
    for (int it = 0; it < 20; ++it) {
        float4 v = *reinterpret_cast<const float4*>(base + (size_t)it * 4 * IN_CH);
        s0 += v.x; s1 += v.y; s2 += v.z; s3 += v.w;
        q0 += v.x * v.x; q1 += v.y * v.y; q2 += v.z * v.z; q3 += v.w * v.w;
    }
    sbuf[trow][quad * 4 + 0] = s0; sbuf[trow][quad * 4 + 1] = s1;
    sbuf[trow][quad * 4 + 2] = s2; sbuf[trow][quad * 4 + 3] = s3;
    qbuf[trow][quad * 4 + 0] = q0; qbuf[trow][quad * 4 + 1] = q1;
    qbuf[trow][quad * 4 + 2] = q2; qbuf[trow][quad * 4 + 3] = q3;
    __syncthreads();
    float ss = sbuf[0][tid] + sbuf[1][tid] + sbuf[2][tid] + sbuf[3][tid];
    float qq = qbuf[0][tid] + qbuf[1][tid] + qbuf[2][tid] + qbuf[3][tid];
    psum[blk * IN_CH + tid] = ss;
    psq [blk * IN_CH + tid] = qq;
}

// ---------- 2. gate1: per-batch logits (8 blocks) ----------
// Old single-block gate pulled 819KB through ONE CU's L2 port (~5-10us).
// Now block b handles batch b: 100 coalesced loads/thread + LDS tree (~1us).
__global__ __launch_bounds__(256) void gate1_kernel(
    const float* __restrict__ psum, const float* __restrict__ psq,
    const float* __restrict__ gate_w, const float* __restrict__ gate_b,
    const float* __restrict__ tau, float* __restrict__ logits) {
    __shared__ float red[2][256];
    const int tid = threadIdx.x;
    const int b   = blockIdx.x;
    float s = 0.f, q = 0.f;
#pragma unroll
    for (int p = 0; p < RCHK; ++p) {
        s += psum[(b * RCHK + p) * IN_CH + tid];
        q += psq [(b * RCHK + p) * IN_CH + tid];
    }
    float mean = s * (1.f / 4000.f);
    float var  = (q - s * s * (1.f / 4000.f)) * (1.f / 3999.f);  // ddof=1
    float sd   = sqrtf(fmaxf(var, 0.f));
    red[0][tid] = mean * gate_w[tid]       + sd * gate_w[256 + tid];
    red[1][tid] = mean * gate_w[512 + tid] + sd * gate_w[768 + tid];
    __syncthreads();
    for (int st = 128; st > 0; st >>= 1) {
        if (tid < st) {
            red[0][tid] += red[0][tid + st];
            red[1][tid] += red[1][tid + st];
        }
        __syncthreads();
    }
    if (tid < 2)
        logits[b * 2 + tid] = tau[0] * (red[tid][0] + gate_b[tid]);
}

// ---------- 3. fused GEMM1(relu)+GEMM2 -> mixed output (R12/R15 core) ----
// Main loop byte-frozen. probs -> inline per-thread softmax from logits
// (2 broadcast loads + 2 exp per row at the two use sites; transient regs).
// Block 0 tid 0 writes the two losses in the prologue.
__global__ __launch_bounds__(256, 2) void gemm_kernel(
    const float* __restrict__ x,
    const unsigned short* __restrict__ w1b,   // [2048][256] bf16
    const unsigned short* __restrict__ w2b,   // [256][2048] bf16
    const float* __restrict__ b1,
    const float* __restrict__ logits,         // [16]
    float* __restrict__ losses,               // [2]
    unsigned short* __restrict__ mix) {       // [32000][256] bf16 (pre-mixed)
    __shared__ __align__(16) unsigned short w1c[64 * 256];   // 32 KB
    __shared__ __align__(16) unsigned short w2c[256 * 64];   // 32 KB
    __shared__ __align__(16) unsigned short f1t[64 * F1LD];  // 8.75 KB

    const int tid   = threadIdx.x;
    const int lane  = tid & 63;
    const int wv    = tid >> 6;       // 0..3
    const int rb    = wv & 1;         // 32-row band
    const int ch    = wv >> 1;        // 0..1 oc half (128 each)
    const int m0    = blockIdx.x * 64;
    const int l15   = lane & 15;
    const int lg    = lane >> 4;      // 0..3

    if (blockIdx.x == 0 && tid == 0) {    // losses (once, ~60 flops)
        float i0 = 0.f, i1 = 0.f, sp = 0.f;
        for (int b = 0; b < NB; ++b) {
            float q0, q1;
            spair(logits, b, q0, q1);
            i0 += q0; i1 += q1;
            float nrm = sqrtf(q0 * q0 + q1 * q1) + 1e-8f;
            sp += (q0 + q1) / nrm;
        }
        losses[0] = 0.1f * sp * (1.f / 8.f);
        i0 *= (1.f / 8.f); i1 *= (1.f / 8.f);
        float meanI = 0.5f * (i0 + i1);
        float stdI  = fabsf(i0 - i1) * 0.7071067811865476f;
        float cv = stdI / (meanI + 1e-8f);
        losses[1] = 0.01f * cv * cv;
    }

    bf16x8 xr[2][8];
#pragma unroll
    for (int rt = 0; rt < 2; ++rt) {
        const float* xrow = x + (size_t)(m0 + rb * 32 + rt * 16 + l15) * IN_CH;
#pragma unroll
        for (int kk = 0; kk < 8; ++kk) {
            float4 v0 = *reinterpret_cast<const float4*>(xrow + kk * 32 + lg * 8);
            float4 v1 = *reinterpret_cast<const float4*>(xrow + kk * 32 + lg * 8 + 4);
            bf16x8 h;
            h[0] = (__bf16)v0.x; h[1] = (__bf16)v0.y; h[2] = (__bf16)v0.z; h[3] = (__bf16)v0.w;
            h[4] = (__bf16)v1.x; h[5] = (__bf16)v1.y; h[6] = (__bf16)v1.z; h[7] = (__bf16)v1.w;
            xr[rt][kk] = h;
        }
    }

    f32x4 acc2[2][8];
#pragma unroll
    for (int rt = 0; rt < 2; ++rt)
#pragma unroll
        for (int t = 0; t < 8; ++t) { acc2[rt][t][0]=0.f; acc2[rt][t][1]=0.f; acc2[rt][t][2]=0.f; acc2[rt][t][3]=0.f; }

#pragma unroll 1
    for (int chunk = 0; chunk < 32; ++chunk) {
        {
            const int h0 = chunk * 64;
            const unsigned short* w1s = w1b + (size_t)h0 * IN_CH;
            const unsigned short* w2s = w2b + h0;
#pragma unroll
            for (int i = 0; i < 8; ++i) {
                int seg = i * 4 + wv;                       // 0..31
                int r1 = seg * 2 + (lane >> 5);
                int c1 = ((lane & 31) * 8) ^ ((r1 & 7) << 3);
                GLOAD_LDS16(w1s + r1 * 256 + c1, &w1c[seg * 512]);
                int r2 = seg * 8 + (lane >> 3);
                int c2 = ((lane & 7) * 8) ^ ((r2 & 7) << 3);
                GLOAD_LDS16(w2s + (size_t)r2 * HIDDEN + c2, &w2c[seg * 512]);
            }
        }

        __syncthreads();   // [A] vmcnt drained -> weights ready

        f32x4 acc1[2][2];
#pragma unroll
        for (int rt = 0; rt < 2; ++rt)
#pragma unroll
            for (int ht = 0; ht < 2; ++ht) { acc1[rt][ht][0]=0.f; acc1[rt][ht][1]=0.f; acc1[rt][ht][2]=0.f; acc1[rt][ht][3]=0.f; }
#pragma unroll
        for (int kk = 0; kk < 8; ++kk) {
            const int kE = kk * 32 + lg * 8;
            bf16x8 bb[2];
#pragma unroll
            for (int ht = 0; ht < 2; ++ht) {
                const int hl = ch * 32 + ht * 16 + l15;
                bb[ht] = *reinterpret_cast<const bf16x8*>(
                    &w1c[hl * 256 + (kE ^ ((hl & 7) << 3))]);
            }
#pragma unroll
            for (int rt = 0; rt < 2; ++rt)
#pragma unroll
                for (int ht = 0; ht < 2; ++ht)
                    acc1[rt][ht] = __builtin_amdgcn_mfma_f32_16x16x32_bf16(
                        xr[rt][kk], bb[ht], acc1[rt][ht], 0, 0, 0);
        }
#pragma unroll
        for (int ht = 0; ht < 2; ++ht) {
            const int hl = ch * 32 + ht * 16 + l15;
            const float bias = b1[chunk * 64 + hl];   // L2-hit scalar
#pragma unroll
            for (int rt = 0; rt < 2; ++rt)
#pragma unroll
                for (int r = 0; r < 4; ++r) {
                    float v = fmaxf(acc1[rt][ht][r] + bias, 0.f);
                    int rr = rb * 32 + rt * 16 + lg * 4 + r;
                    f1t[rr * F1LD + hl] = bfbits(v);
                }
        }

        __syncthreads();   // [B] f1t ready

#pragma unroll
        for (int kk = 0; kk < 2; ++kk) {
            const int kE = kk * 32 + lg * 8;
            bf16x8 a2[2];
#pragma unroll
            for (int rt = 0; rt < 2; ++rt)
                a2[rt] = *reinterpret_cast<const bf16x8*>(
                    &f1t[(rb * 32 + rt * 16 + l15) * F1LD + kE]);
#pragma unroll
            for (int t = 0; t < 8; ++t) {
                int oc = ch * 128 + t * 16 + l15;
                bf16x8 b2 = *reinterpret_cast<const bf16x8*>(
                    &w2c[oc * 64 + (kE ^ ((oc & 7) << 3))]);
#pragma unroll
                for (int rt = 0; rt < 2; ++rt)
                    acc2[rt][t] = __builtin_amdgcn_mfma_f32_16x16x32_bf16(
                        a2[rt], b2, acc2[rt][t], 0, 0, 0);
            }
        }

        if (chunk == 3) {   // small branch done: rescale so p0*acc2 = p0*full+p1*small
#pragma unroll
            for (int rt = 0; rt < 2; ++rt)
#pragma unroll
                for (int r = 0; r < 4; ++r) {
                    int rr = m0 + rb * 32 + rt * 16 + lg * 4 + r;
                    int bb = rr / 4000;
                    float p0, p1;
                    spair(logits, bb, p0, p1);
                    float ratio = (p0 + p1) / fmaxf(p0, 1e-30f);
#pragma unroll
                    for (int t = 0; t < 8; ++t)
                        acc2[rt][t][r] *= ratio;
                }
        }

        __syncthreads();   // [C] reads done -> next stage may overwrite
    }
    // final: mix = p0 * acc2 (= p0*full + p1*small)
#pragma unroll
    for (int rt = 0; rt < 2; ++rt)
#pragma unroll
        for (int r = 0; r < 4; ++r) {
            int rr = m0 + rb * 32 + rt * 16 + lg * 4 + r;
            int bb = rr / 4000;
            float p0, p1;
            spair(logits, bb, p0, p1);
#pragma unroll
            for (int t = 0; t < 8; ++t) {
                int oc = ch * 128 + t * 16 + l15;
                mix[(size_t)rr * OUT_CH + oc] = bfbits(p0 * acc2[rt][t][r]);
            }
        }
}

// ---------- 4. depthwise conv: window-in-registers (frozen: R16) ----------
#define CT3 32                  // t outputs per block
#define CR3 (CT3 + 38)          // 70 staged rows
__global__ __launch_bounds__(256, 2) void conv_kernel(
    const unsigned short* __restrict__ mix,
    const float* __restrict__ conv_w,   // [256][1][39]
    float* __restrict__ out) {
    __shared__ __align__(16) unsigned short lds[CR3 * 256];   // 35 KB

    const int tid = threadIdx.x;
    const int blk = blockIdx.x;
    const int b   = blk / 125;
    const int t0  = (blk % 125) * CT3;

#pragma unroll
    for (int it = 0; it < 9; ++it) {
        int chunk = it * 256 + tid;
        if (it == 8 && tid >= 192) break;
        int e = chunk * 8;
        int s = e >> 8, c = e & 255;
        int t = t0 - 19 + s;
        u16x8 o;
        if (t >= 0 && t < NT) {
            o = *reinterpret_cast<const u16x8*>(&mix[((size_t)b * NT + t) * OUT_CH + c]);
        } else {
#pragma unroll
            for (int k = 0; k < 8; ++k) o[k] = 0;
        }
        *reinterpret_cast<u16x8*>(&lds[s * 256 + c]) = o;
    }
    __syncthreads();

    const int c = tid;
    float cw[39];
#pragma unroll
    for (int j = 0; j < 39; ++j) cw[j] = conv_w[c * 39 + j];

    float vwin[CR3];
#pragma unroll
    for (int i = 0; i < CR3; ++i)
        vwin[i] = bf2f(lds[i * 256 + c]);

    float* outb = out + ((size_t)b * NT + t0) * OUT_CH + c;
#pragma unroll
    for (int g = 0; g < 4; ++g) {
        float acc[8];
#pragma unroll
        for (int o = 0; o < 8; ++o) {
            float a = vwin[g * 8 + o + 19];      // identity (xp + conv)
#pragma unroll
            for (int j = 0; j < 39; ++j)
                a += cw[j] * vwin[g * 8 + o + j];
            acc[o] = a;
        }
#pragma unroll
        for (int o = 0; o < 8; ++o)
            outb[(size_t)(g * 8 + o) * OUT_CH] = acc[o];
    }
}

// ---------- launch ----------
extern "C" void kernel_launch(void* const* d_in, const int* in_sizes, int n_in,
                              void* d_out, int out_size, void* d_ws, size_t ws_size,
                              hipStream_t stream) {
    const float* x      = (const float*)d_in[0];
    const float* w1     = (const float*)d_in[1];
    const float* b1     = (const float*)d_in[2];
    const float* w2     = (const float*)d_in[3];
    const float* conv_w = (const float*)d_in[4];
    const float* gate_w = (const float*)d_in[5];
    const float* gate_b = (const float*)d_in[6];
    const float* tau    = (const float*)d_in[7];
    float* out = (float*)d_out;

    char* ws = (char*)d_ws;
    unsigned short* w1b = (unsigned short*)(ws);
    unsigned short* w2b = (unsigned short*)(ws + 1048576);
    unsigned short* mix = (unsigned short*)(ws + 2097152);
    float* psum   = (float*)(ws + 2097152 + 16384000);
    float* psq    = psum + NB * RCHK * IN_CH;
    float* logits = psq + NB * RCHK * IN_CH;

    prep_kernel<<<dim3(1024 + NB * RCHK), dim3(256), 0, stream>>>(
        w1, w1b, w2, w2b, x, psum, psq);
    gate1_kernel<<<dim3(NB), dim3(256), 0, stream>>>(psum, psq, gate_w, gate_b,
                                                     tau, logits);
    gemm_kernel<<<dim3(500), dim3(256), 0, stream>>>(x, w1b, w2b, b1, logits,
                                                     out + 8192000, mix);
    conv_kernel<<<dim3(1000), dim3(256), 0, stream>>>(mix, conv_w, out);
}